// Round 1
// baseline (1273.104 us; speedup 1.0000x reference)
//
#include <hip/hip_runtime.h>
#include <math.h>

// ---------------------------------------------------------------------------
// BridgeLayer fp32 baseline.
// Shapes: B=1, T=1024, N=8, H=8, D_S=1024 (DH_S=128), D_R=512 (DH_R=64), TOPK=4
// ---------------------------------------------------------------------------

#define T_DIM 1024
#define N_SLOT 8
#define DS 1024
#define DR 512
#define NH 8
#define DHS 128
#define DHR 64

// ---------------------------------------------------------------- rmsnorm ---
__global__ __launch_bounds__(256) void rmsnorm_kernel(
    const float* __restrict__ x, const float* __restrict__ w,
    float* __restrict__ y, int width) {
  const int row = blockIdx.x;
  const int tid = threadIdx.x;
  const size_t base = (size_t)row * width;
  float ss = 0.f;
  for (int i = tid; i < width; i += 256) {
    float v = x[base + i];
    ss += v * v;
  }
  for (int m = 32; m >= 1; m >>= 1) ss += __shfl_xor(ss, m);
  __shared__ float red[4];
  const int wave = tid >> 6, lane = tid & 63;
  if (lane == 0) red[wave] = ss;
  __syncthreads();
  float total = red[0] + red[1] + red[2] + red[3];
  float scale = rsqrtf(total / (float)width + 1e-6f);
  for (int i = tid; i < width; i += 256) {
    y[base + i] = x[base + i] * scale * w[i];
  }
}

// ------------------------------------------------------------------- gemm ---
// C[M,N] (+)= A[M,K] @ B[K,N], all row-major fp32. BS x BS tile, TT x TT micro.
// Requires M%BS==0, N%BS==0, K%16==0.
template <int BS, int TT, bool ACCUM>
__global__ __launch_bounds__(256) void gemm_kernel(
    const float* __restrict__ A, const float* __restrict__ B,
    float* __restrict__ C, int M, int N, int K) {
  __shared__ __align__(16) float Ast[16][BS + 4];  // [kk][row] (A transposed)
  __shared__ __align__(16) float Bs[16][BS + 4];   // [kk][col]
  const int tid = threadIdx.x;
  const int tx = tid & 15, ty = tid >> 4;
  const int row0 = blockIdx.y * BS, col0 = blockIdx.x * BS;
  float acc[TT][TT] = {};
  constexpr int NF4 = BS * 16 / 4;  // float4 chunks per tile per matrix
  for (int k0 = 0; k0 < K; k0 += 16) {
    __syncthreads();  // protect LDS from previous iteration's readers
    for (int l = tid; l < NF4; l += 256) {
      int lr = l >> 2, lk = (l & 3) << 2;
      float4 a4 = *(const float4*)&A[(size_t)(row0 + lr) * K + k0 + lk];
      Ast[lk + 0][lr] = a4.x;
      Ast[lk + 1][lr] = a4.y;
      Ast[lk + 2][lr] = a4.z;
      Ast[lk + 3][lr] = a4.w;
      int bkk = l / (BS / 4), bc = (l % (BS / 4)) << 2;
      float4 b4 = *(const float4*)&B[(size_t)(k0 + bkk) * N + col0 + bc];
      *(float4*)&Bs[bkk][bc] = b4;
    }
    __syncthreads();
#pragma unroll
    for (int kk = 0; kk < 16; ++kk) {
      float av[TT], bv[TT];
#pragma unroll
      for (int u = 0; u < TT; u += 4) {
        *(float4*)&av[u] = *(const float4*)&Ast[kk][ty * TT + u];
        *(float4*)&bv[u] = *(const float4*)&Bs[kk][tx * TT + u];
      }
#pragma unroll
      for (int i = 0; i < TT; ++i)
#pragma unroll
        for (int j = 0; j < TT; ++j) acc[i][j] += av[i] * bv[j];
    }
  }
#pragma unroll
  for (int i = 0; i < TT; ++i) {
    size_t crow = (size_t)(row0 + ty * TT + i) * N + col0;
#pragma unroll
    for (int j = 0; j < TT; j += 4) {
      float4 cv;
      if (ACCUM) {
        cv = *(const float4*)&C[crow + tx * TT + j];
        cv.x += acc[i][j + 0];
        cv.y += acc[i][j + 1];
        cv.z += acc[i][j + 2];
        cv.w += acc[i][j + 3];
      } else {
        cv = make_float4(acc[i][j], acc[i][j + 1], acc[i][j + 2], acc[i][j + 3]);
      }
      *(float4*)&C[crow + tx * TT + j] = cv;
    }
  }
}

// ---------------------------------------------- part1 + part3 (per t row) ---
// dots[h][n] = q[t,h,:]·k[t,n,h,:]; part1 softmax over n per h -> attn1;
// sp[n] = scale_s * sum_h dots; top-4 softmax -> w8; outS = s + gate*r_sparse.
__global__ __launch_bounds__(256) void part1_kernel(
    const float* __restrict__ s, const float* __restrict__ gv,
    const float* __restrict__ q, const float* __restrict__ k,
    const float* __restrict__ v, float* __restrict__ attn1,
    float* __restrict__ outS) {
  __shared__ float qs[DS];
  __shared__ float dots[NH][N_SLOT];
  __shared__ float wattn[NH][N_SLOT];
  __shared__ float w8[N_SLOT];
  __shared__ float spv[N_SLOT];
  __shared__ float gateL;
  const int t = blockIdx.x;
  const int tid = threadIdx.x;
  for (int i = tid; i < DS; i += 256) qs[i] = q[(size_t)t * DS + i];
  __syncthreads();
  const int wave = tid >> 6, lane = tid & 63;
#pragma unroll
  for (int e = 0; e < 16; ++e) {
    int pair = wave * 16 + e;
    int h = pair >> 3, n = pair & 7;
    const float* krow = &k[((size_t)t * N_SLOT + n) * DS + h * DHS];
    float a = qs[h * DHS + lane] * krow[lane] +
              qs[h * DHS + 64 + lane] * krow[64 + lane];
    for (int m = 32; m >= 1; m >>= 1) a += __shfl_xor(a, m);
    if (lane == 0) dots[h][n] = a;
  }
  __syncthreads();
  const float scale_s = 0.08838834764831845f;  // 128^-0.5
  if (tid < 8) {
    int h = tid;
    float vmax = -1e30f;
    for (int n = 0; n < 8; ++n) vmax = fmaxf(vmax, dots[h][n] * scale_s);
    float sum = 0.f;
    for (int n = 0; n < 8; ++n) {
      float e = __expf(dots[h][n] * scale_s - vmax);
      wattn[h][n] = e;
      sum += e;
    }
    float inv = 1.f / sum;
    for (int n = 0; n < 8; ++n) wattn[h][n] *= inv;
  }
  if (tid >= 64 && tid < 72) {
    int n = tid - 64;
    float sp = 0.f;
    for (int h = 0; h < 8; ++h) sp += dots[h][n];
    spv[n] = sp * scale_s;
  }
  __syncthreads();
  if (tid == 0) {
    float sv[8];
    for (int n = 0; n < 8; ++n) sv[n] = spv[n];
    bool used[8] = {};
    float vals[4];
    int idxs[4];
    for (int kk = 0; kk < 4; ++kk) {
      float best = -1e30f;
      int bi = 0;
      for (int n = 0; n < 8; ++n)
        if (!used[n] && sv[n] > best) { best = sv[n]; bi = n; }
      used[bi] = true;
      vals[kk] = best;
      idxs[kk] = bi;
    }
    float mx = vals[0];  // first pick is global max
    float wv[4];
    float sum = 0.f;
    for (int kk = 0; kk < 4; ++kk) {
      wv[kk] = __expf(vals[kk] - mx);
      sum += wv[kk];
    }
    float inv = 1.f / sum;
    for (int n = 0; n < 8; ++n) w8[n] = 0.f;
    for (int kk = 0; kk < 4; ++kk) w8[idxs[kk]] = wv[kk] * inv;
    gateL = gv[t];
  }
  __syncthreads();
  const float gate = gateL;
#pragma unroll
  for (int jj = 0; jj < 4; ++jj) {
    int d = tid + 256 * jj;
    int hh = d >> 7;
    float a1 = 0.f, a2 = 0.f;
#pragma unroll
    for (int n = 0; n < 8; ++n) {
      float vv = v[((size_t)t * N_SLOT + n) * DS + d];
      a1 += wattn[hh][n] * vv;
      a2 += w8[n] * vv;
    }
    attn1[(size_t)t * DS + d] = a1;
    outS[(size_t)t * DS + d] = s[(size_t)t * DS + d] + gate * a2;
  }
}

// ------------------------------------------------- part2 flash attention ----
// Q rows = (t*8+n) of qr (8192 x 512, head slice h*64..); keys/values = kr/vr
// (1024 x 512). Causal: p <= t. Q-tile 32 rows (4 t values), K-tile 64.
__global__ __launch_bounds__(256) void flash_kernel(
    const float* __restrict__ qr, const float* __restrict__ kr,
    const float* __restrict__ vr, float* __restrict__ rat) {
  __shared__ __align__(16) float Qs[32][68];
  __shared__ __align__(16) float Ks[64][68];
  __shared__ __align__(16) float Vs[64][68];
  __shared__ float Pt[64][36];  // transposed scores [col][row]
  __shared__ float mL[32], lL[32], aL[32];
  const int tid = threadIdx.x;
  const int tx = tid & 15, ty = tid >> 4;
  const int h = blockIdx.y;
  const int rbase = blockIdx.x * 32;
  const float scale_r = 0.125f;  // 64^-0.5
  // load + pre-scale Q tile
  for (int l = tid; l < 512; l += 256) {
    int r = l >> 4, d4 = (l & 15) << 2;
    float4 qv = *(const float4*)&qr[(size_t)(rbase + r) * DR + h * DHR + d4];
    qv.x *= scale_r; qv.y *= scale_r; qv.z *= scale_r; qv.w *= scale_r;
    *(float4*)&Qs[r][d4] = qv;
  }
  if (tid < 32) { mL[tid] = -1e30f; lL[tid] = 0.f; }
  float o[2][4] = {};
  const int tmax = (rbase >> 3) + 3;
  const int ntiles = (tmax >> 6) + 1;
  for (int pt = 0; pt < ntiles; ++pt) {
    const int p0 = pt << 6;
    for (int l = tid; l < 1024; l += 256) {
      int c = l >> 4, d4 = (l & 15) << 2;
      *(float4*)&Ks[c][d4] = *(const float4*)&kr[(size_t)(p0 + c) * DR + h * DHR + d4];
      *(float4*)&Vs[c][d4] = *(const float4*)&vr[(size_t)(p0 + c) * DR + h * DHR + d4];
    }
    __syncthreads();
    // S = Q @ K^T : rows ty+16i (i<2), cols tx+16j (j<4)
    float sc[2][4] = {};
#pragma unroll
    for (int d4 = 0; d4 < 64; d4 += 4) {
      float4 q0 = *(const float4*)&Qs[ty][d4];
      float4 q1 = *(const float4*)&Qs[ty + 16][d4];
#pragma unroll
      for (int j = 0; j < 4; ++j) {
        float4 kv = *(const float4*)&Ks[tx + 16 * j][d4];
        sc[0][j] += q0.x * kv.x + q0.y * kv.y + q0.z * kv.z + q0.w * kv.w;
        sc[1][j] += q1.x * kv.x + q1.y * kv.y + q1.z * kv.z + q1.w * kv.w;
      }
    }
#pragma unroll
    for (int i = 0; i < 2; ++i) {
      int trow = (rbase + ty + 16 * i) >> 3;
#pragma unroll
      for (int j = 0; j < 4; ++j) {
        int p = p0 + tx + 16 * j;
        Pt[tx + 16 * j][ty + 16 * i] = (p <= trow) ? sc[i][j] : -1e30f;
      }
    }
    __syncthreads();
    if (tid < 32) {
      const int r = tid;
      float mold = mL[r];
      float mx = mold;
      for (int c = 0; c < 64; ++c) mx = fmaxf(mx, Pt[c][r]);
      float sum = 0.f;
      for (int c = 0; c < 64; ++c) {
        float e = __expf(Pt[c][r] - mx);
        Pt[c][r] = e;
        sum += e;
      }
      float alpha = __expf(mold - mx);
      lL[r] = alpha * lL[r] + sum;
      mL[r] = mx;
      aL[r] = alpha;
    }
    __syncthreads();
#pragma unroll
    for (int i = 0; i < 2; ++i) {
      float al = aL[ty + 16 * i];
      o[i][0] *= al; o[i][1] *= al; o[i][2] *= al; o[i][3] *= al;
    }
    for (int c = 0; c < 64; ++c) {
      float4 vv = *(const float4*)&Vs[c][tx * 4];
      float pa = Pt[c][ty];
      float pb = Pt[c][ty + 16];
      o[0][0] += pa * vv.x; o[0][1] += pa * vv.y;
      o[0][2] += pa * vv.z; o[0][3] += pa * vv.w;
      o[1][0] += pb * vv.x; o[1][1] += pb * vv.y;
      o[1][2] += pb * vv.z; o[1][3] += pb * vv.w;
    }
    __syncthreads();
  }
#pragma unroll
  for (int i = 0; i < 2; ++i) {
    float inv = 1.f / lL[ty + 16 * i];
    float4 ov = make_float4(o[i][0] * inv, o[i][1] * inv, o[i][2] * inv, o[i][3] * inv);
    *(float4*)&rat[(size_t)(rbase + ty + 16 * i) * DR + h * DHR + tx * 4] = ov;
  }
}

// ------------------------------------------------------------------- copy ---
__global__ __launch_bounds__(256) void copy4_kernel(const float4* __restrict__ in,
                                                    float4* __restrict__ out,
                                                    int n4) {
  int i = blockIdx.x * 256 + threadIdx.x;
  if (i < n4) out[i] = in[i];
}

// ----------------------------------------------------------------- launch ---
extern "C" void kernel_launch(void* const* d_in, const int* in_sizes, int n_in,
                              void* d_out, int out_size, void* d_ws,
                              size_t ws_size, hipStream_t stream) {
  const float* s   = (const float*)d_in[0];   // (1024,1024)
  const float* r   = (const float*)d_in[1];   // (1024,8,512)
  const float* gv  = (const float*)d_in[2];   // (1024,)
  const float* nsw = (const float*)d_in[3];   // (1024,)
  const float* nrw = (const float*)d_in[4];   // (512,)
  const float* Wsq = (const float*)d_in[5];
  const float* Wsk = (const float*)d_in[6];
  const float* Wsv = (const float*)d_in[7];
  const float* Wso = (const float*)d_in[8];
  const float* Wrq = (const float*)d_in[9];
  const float* Wrk = (const float*)d_in[10];
  const float* Wrv = (const float*)d_in[11];
  const float* Wro = (const float*)d_in[12];

  float* outS = (float*)d_out;            // 1048576
  float* outR = outS + 1048576;           // 4194304

  float* ws  = (float*)d_ws;
  float* s_n = ws;                        // 1048576  (reused as attn1 later)
  float* r_n = s_n + 1048576;             // 4194304  (reused as rat later)
  float* q   = r_n + 4194304;             // 1048576
  float* k   = q + 1048576;               // 8388608
  float* v   = k + 8388608;               // 8388608
  float* qr  = v + 8388608;               // 4194304
  float* kr  = qr + 4194304;              // 524288
  float* vr  = kr + 524288;               // 524288
  float* attn1 = s_n;  // s_n dead after Wrk/Wrv gemms
  float* rat   = r_n;  // r_n dead after Wrq gemm

  // RMS norms
  rmsnorm_kernel<<<1024, 256, 0, stream>>>(s, nsw, s_n, DS);
  rmsnorm_kernel<<<8192, 256, 0, stream>>>(r, nrw, r_n, DR);

  // Projections
  gemm_kernel<64, 4, false><<<dim3(16, 16), 256, 0, stream>>>(s_n, Wsq, q, 1024, 1024, 1024);
  gemm_kernel<128, 8, false><<<dim3(8, 64), 256, 0, stream>>>(r_n, Wsk, k, 8192, 1024, 512);
  gemm_kernel<128, 8, false><<<dim3(8, 64), 256, 0, stream>>>(r_n, Wsv, v, 8192, 1024, 512);
  gemm_kernel<128, 8, false><<<dim3(4, 64), 256, 0, stream>>>(r_n, Wrq, qr, 8192, 512, 512);
  gemm_kernel<64, 4, false><<<dim3(8, 16), 256, 0, stream>>>(s_n, Wrk, kr, 1024, 512, 1024);
  gemm_kernel<64, 4, false><<<dim3(8, 16), 256, 0, stream>>>(s_n, Wrv, vr, 1024, 512, 1024);

  // Part 1 (slot attention) + part 3 (top-k sparse writeback) -> attn1, outS init
  part1_kernel<<<1024, 256, 0, stream>>>(s, gv, q, k, v, attn1, outS);
  // outS += attn1 @ Wso
  gemm_kernel<64, 4, true><<<dim3(16, 16), 256, 0, stream>>>(attn1, Wso, outS, 1024, 1024, 1024);

  // Part 2: r2 = r + flash(qr,kr,vr) @ Wro
  copy4_kernel<<<4096, 256, 0, stream>>>((const float4*)r, (float4*)outR, 1048576);
  flash_kernel<<<dim3(256, 8), 256, 0, stream>>>(qr, kr, vr, rat);
  gemm_kernel<128, 8, true><<<dim3(4, 64), 256, 0, stream>>>(rat, Wro, outR, 8192, 512, 512);
}

// Round 3
// 959.139 us; speedup vs baseline: 1.3273x; 1.3273x over previous
//
#include <hip/hip_runtime.h>
#include <hip/hip_bf16.h>
#include <math.h>

// ---------------------------------------------------------------------------
// BridgeLayer: bf16-MFMA GEMMs + fp32 attention; fp32 top-k score path.
// Shapes: B=1, T=1024, N=8, H=8, D_S=1024 (DH_S=128), D_R=512 (DH_R=64), TOPK=4
// ---------------------------------------------------------------------------

#define T_DIM 1024
#define N_SLOT 8
#define DS 1024
#define DR 512
#define NH 8
#define DHS 128
#define DHR 64

typedef __attribute__((ext_vector_type(8))) short short8v;
typedef __attribute__((ext_vector_type(4))) float floatx4;

// ---------------------------------------------------------------- rmsnorm ---
// bf16 out always; fp32 out if y32 != nullptr.
__global__ __launch_bounds__(256) void rmsnorm_bf16_kernel(
    const float* __restrict__ x, const float* __restrict__ w,
    __hip_bfloat16* __restrict__ y, float* __restrict__ y32, int width) {
  const int row = blockIdx.x;
  const int tid = threadIdx.x;
  const size_t base = (size_t)row * width;
  float ss = 0.f;
  for (int i = tid; i < width; i += 256) {
    float v = x[base + i];
    ss += v * v;
  }
  for (int m = 32; m >= 1; m >>= 1) ss += __shfl_xor(ss, m);
  __shared__ float red[4];
  const int wave = tid >> 6, lane = tid & 63;
  if (lane == 0) red[wave] = ss;
  __syncthreads();
  float total = red[0] + red[1] + red[2] + red[3];
  float scale = rsqrtf(total / (float)width + 1e-6f);
  for (int i = tid; i < width; i += 256) {
    float val = x[base + i] * scale * w[i];
    y[base + i] = __float2bfloat16(val);
    if (y32) y32[base + i] = val;
  }
}

// -------------------------------------------------- weight transpose+cast ---
// Wt[n][k] = bf16(W[k][n]).  grid = (N/32, K/32), block = 256.
__global__ __launch_bounds__(256) void transpose_bf16_kernel(
    const float* __restrict__ W, __hip_bfloat16* __restrict__ Wt, int K, int N) {
  __shared__ float t[32][33];
  const int tx = threadIdx.x & 31, ty = threadIdx.x >> 5;  // 32 x 8
  const int n0 = blockIdx.x * 32, k0 = blockIdx.y * 32;
#pragma unroll
  for (int i = 0; i < 4; ++i) {
    int kk = ty + i * 8;
    t[kk][tx] = W[(size_t)(k0 + kk) * N + n0 + tx];
  }
  __syncthreads();
#pragma unroll
  for (int i = 0; i < 4; ++i) {
    int nn = ty + i * 8;
    Wt[(size_t)(n0 + nn) * K + k0 + tx] = __float2bfloat16(t[tx][nn]);
  }
}

// --------------------------------------------------------------- fp32 gemm --
// C[M,N] (+)= A[M,K] @ B.  BT=false: B is [K][N]; BT=true: B is [N][K] (NT).
// BS x BS tile, TT x TT micro. Requires M%BS==0, N%BS==0, K%16==0.
template <int BS, int TT, bool ACCUM, bool BT>
__global__ __launch_bounds__(256) void gemm_f32_kernel(
    const float* __restrict__ A, const float* __restrict__ B,
    float* __restrict__ C, int M, int N, int K) {
  __shared__ __align__(16) float Ast[16][BS + 4];  // [kk][row]
  __shared__ __align__(16) float Bs[16][BS + 4];   // [kk][col]
  const int tid = threadIdx.x;
  const int tx = tid & 15, ty = tid >> 4;
  const int row0 = blockIdx.y * BS, col0 = blockIdx.x * BS;
  float acc[TT][TT] = {};
  constexpr int NF4 = BS * 16 / 4;
  for (int k0 = 0; k0 < K; k0 += 16) {
    __syncthreads();
    for (int l = tid; l < NF4; l += 256) {
      int lr = l >> 2, lk = (l & 3) << 2;
      float4 a4 = *(const float4*)&A[(size_t)(row0 + lr) * K + k0 + lk];
      Ast[lk + 0][lr] = a4.x;
      Ast[lk + 1][lr] = a4.y;
      Ast[lk + 2][lr] = a4.z;
      Ast[lk + 3][lr] = a4.w;
      if (BT) {
        float4 b4 = *(const float4*)&B[(size_t)(col0 + lr) * K + k0 + lk];
        Bs[lk + 0][lr] = b4.x;
        Bs[lk + 1][lr] = b4.y;
        Bs[lk + 2][lr] = b4.z;
        Bs[lk + 3][lr] = b4.w;
      } else {
        int bkk = l / (BS / 4), bc = (l % (BS / 4)) << 2;
        float4 b4 = *(const float4*)&B[(size_t)(k0 + bkk) * N + col0 + bc];
        *(float4*)&Bs[bkk][bc] = b4;
      }
    }
    __syncthreads();
#pragma unroll
    for (int kk = 0; kk < 16; ++kk) {
      float av[TT], bv[TT];
#pragma unroll
      for (int u = 0; u < TT; u += 4) {
        *(float4*)&av[u] = *(const float4*)&Ast[kk][ty * TT + u];
        *(float4*)&bv[u] = *(const float4*)&Bs[kk][tx * TT + u];
      }
#pragma unroll
      for (int i = 0; i < TT; ++i)
#pragma unroll
        for (int j = 0; j < TT; ++j) acc[i][j] += av[i] * bv[j];
    }
  }
#pragma unroll
  for (int i = 0; i < TT; ++i) {
    size_t crow = (size_t)(row0 + ty * TT + i) * N + col0;
#pragma unroll
    for (int j = 0; j < TT; j += 4) {
      float4 cv;
      if (ACCUM) {
        cv = *(const float4*)&C[crow + tx * TT + j];
        cv.x += acc[i][j + 0];
        cv.y += acc[i][j + 1];
        cv.z += acc[i][j + 2];
        cv.w += acc[i][j + 3];
      } else {
        cv = make_float4(acc[i][j], acc[i][j + 1], acc[i][j + 2], acc[i][j + 3]);
      }
      *(float4*)&C[crow + tx * TT + j] = cv;
    }
  }
}

// -------------------------------------------------------------- MFMA gemm ---
// C[M,N] (+)= A[M,K] @ Bt[N,K]^T.  A,Bt bf16 row-major; C fp32.
template <bool ACCUM>
__global__ __launch_bounds__(256) void mfma_gemm_kernel(
    const __hip_bfloat16* __restrict__ A, const __hip_bfloat16* __restrict__ Bt,
    float* __restrict__ C, int M, int N, int K) {
  __shared__ __align__(16) __hip_bfloat16 As[128][40];
  __shared__ __align__(16) __hip_bfloat16 Bs[128][40];
  const int tid = threadIdx.x;
  const int lane = tid & 63, wave = tid >> 6;
  const int wm = wave >> 1, wn = wave & 1;
  const int l15 = lane & 15, l4 = lane >> 4;
  const int row0 = blockIdx.y * 128, col0 = blockIdx.x * 128;
  floatx4 acc[4][4] = {};
  for (int k0 = 0; k0 < K; k0 += 32) {
    __syncthreads();
#pragma unroll
    for (int g = tid; g < 512; g += 256) {
      int row = g >> 2, c = (g & 3) * 8;
      *(ulonglong2*)&As[row][c] =
          *(const ulonglong2*)&A[(size_t)(row0 + row) * K + k0 + c];
      *(ulonglong2*)&Bs[row][c] =
          *(const ulonglong2*)&Bt[(size_t)(col0 + row) * K + k0 + c];
    }
    __syncthreads();
    short8v af[4], bf[4];
#pragma unroll
    for (int i = 0; i < 4; ++i)
      af[i] = *(const short8v*)&As[wm * 64 + i * 16 + l15][l4 * 8];
#pragma unroll
    for (int j = 0; j < 4; ++j)
      bf[j] = *(const short8v*)&Bs[wn * 64 + j * 16 + l15][l4 * 8];
#pragma unroll
    for (int i = 0; i < 4; ++i)
#pragma unroll
      for (int j = 0; j < 4; ++j)
        acc[i][j] = __builtin_amdgcn_mfma_f32_16x16x32_bf16(af[i], bf[j],
                                                            acc[i][j], 0, 0, 0);
  }
  // C/D layout: col = lane&15, row = (lane>>4)*4 + reg  [m89-verified]
#pragma unroll
  for (int i = 0; i < 4; ++i) {
    int rb = row0 + wm * 64 + i * 16 + l4 * 4;
#pragma unroll
    for (int j = 0; j < 4; ++j) {
      int cb = col0 + wn * 64 + j * 16 + l15;
#pragma unroll
      for (int rg = 0; rg < 4; ++rg) {
        size_t idx = (size_t)(rb + rg) * N + cb;
        if (ACCUM)
          C[idx] += acc[i][j][rg];
        else
          C[idx] = acc[i][j][rg];
      }
    }
  }
}

// ---------------------------------------------- part1 + part3 (per t row) ---
// wattn: softmax over n of per-head q·k (bf16-GEMM q,k — continuous, safe).
// top-k scores sp: fp32 path sp[n] = scale * rs_n * sum_j r*nrw*u  (exact
// reassociation of q·ksp; u = s_n @ (Wsq @ Wsk^T) computed in fp32).
__global__ __launch_bounds__(256) void part1_kernel(
    const float* __restrict__ s, const float* __restrict__ gv,
    const float* __restrict__ q, const float* __restrict__ k,
    const float* __restrict__ v, const float* __restrict__ r,
    const float* __restrict__ nrw, const float* __restrict__ u,
    __hip_bfloat16* __restrict__ attn1, float* __restrict__ outS) {
  __shared__ float qs[DS];
  __shared__ float dots[NH][N_SLOT];
  __shared__ float wattn[NH][N_SLOT];
  __shared__ float w8[N_SLOT];
  __shared__ float spv[N_SLOT];
  __shared__ float gateL;
  const int t = blockIdx.x;
  const int tid = threadIdx.x;
  for (int i = tid; i < DS; i += 256) qs[i] = q[(size_t)t * DS + i];
  __syncthreads();
  const int wave = tid >> 6, lane = tid & 63;
#pragma unroll
  for (int e = 0; e < 16; ++e) {
    int pair = wave * 16 + e;
    int h = pair >> 3, n = pair & 7;
    const float* krow = &k[((size_t)t * N_SLOT + n) * DS + h * DHS];
    float a = qs[h * DHS + lane] * krow[lane] +
              qs[h * DHS + 64 + lane] * krow[64 + lane];
    for (int m = 32; m >= 1; m >>= 1) a += __shfl_xor(a, m);
    if (lane == 0) dots[h][n] = a;
  }
  const float scale_s = 0.08838834764831845f;  // 128^-0.5
  // fp32 sp: wave w handles slots 2w, 2w+1
#pragma unroll
  for (int e = 0; e < 2; ++e) {
    const int n = wave * 2 + e;
    const float* rr = &r[((size_t)t * N_SLOT + n) * DR];
    const float* ub = &u[(size_t)t * DR];
    float ssum = 0.f, dot = 0.f;
#pragma unroll
    for (int jj = 0; jj < 8; ++jj) {
      int j = lane + 64 * jj;
      float rv = rr[j];
      ssum += rv * rv;
      dot += rv * nrw[j] * ub[j];
    }
    for (int m = 32; m >= 1; m >>= 1) {
      ssum += __shfl_xor(ssum, m);
      dot += __shfl_xor(dot, m);
    }
    if (lane == 0) {
      float rs = rsqrtf(ssum / (float)DR + 1e-6f);
      spv[n] = scale_s * rs * dot;
    }
  }
  __syncthreads();
  if (tid < 8) {
    int h = tid;
    float vmax = -1e30f;
    for (int n = 0; n < 8; ++n) vmax = fmaxf(vmax, dots[h][n] * scale_s);
    float sum = 0.f;
    for (int n = 0; n < 8; ++n) {
      float e = __expf(dots[h][n] * scale_s - vmax);
      wattn[h][n] = e;
      sum += e;
    }
    float inv = 1.f / sum;
    for (int n = 0; n < 8; ++n) wattn[h][n] *= inv;
  }
  if (tid == 64) {
    float sv[8];
    for (int n = 0; n < 8; ++n) sv[n] = spv[n];
    bool used[8] = {};
    float vals[4];
    int idxs[4];
    for (int kk = 0; kk < 4; ++kk) {
      float best = -1e30f;
      int bi = 0;
      for (int n = 0; n < 8; ++n)
        if (!used[n] && sv[n] > best) { best = sv[n]; bi = n; }
      used[bi] = true;
      vals[kk] = best;
      idxs[kk] = bi;
    }
    float mx = vals[0];
    float wv[4];
    float sum = 0.f;
    for (int kk = 0; kk < 4; ++kk) {
      wv[kk] = __expf(vals[kk] - mx);
      sum += wv[kk];
    }
    float inv = 1.f / sum;
    for (int n = 0; n < 8; ++n) w8[n] = 0.f;
    for (int kk = 0; kk < 4; ++kk) w8[idxs[kk]] = wv[kk] * inv;
    gateL = gv[t];
  }
  __syncthreads();
  const float gate = gateL;
#pragma unroll
  for (int jj = 0; jj < 4; ++jj) {
    int d = tid + 256 * jj;
    int hh = d >> 7;
    float a1 = 0.f, a2 = 0.f;
#pragma unroll
    for (int n = 0; n < 8; ++n) {
      float vv = v[((size_t)t * N_SLOT + n) * DS + d];
      a1 += wattn[hh][n] * vv;
      a2 += w8[n] * vv;
    }
    attn1[(size_t)t * DS + d] = __float2bfloat16(a1);
    outS[(size_t)t * DS + d] = s[(size_t)t * DS + d] + gate * a2;
  }
}

// ------------------------------------------------- part2 flash attention ----
__global__ __launch_bounds__(256) void flash_kernel(
    const float* __restrict__ qr, const float* __restrict__ kr,
    const float* __restrict__ vr, __hip_bfloat16* __restrict__ rat) {
  __shared__ __align__(16) float Qs[32][68];
  __shared__ __align__(16) float Ks[64][68];
  __shared__ __align__(16) float Vs[64][68];
  __shared__ float Pt[64][36];  // transposed scores [col][row]
  __shared__ float mL[32], lL[32], aL[32];
  const int tid = threadIdx.x;
  const int tx = tid & 15, ty = tid >> 4;
  const int h = blockIdx.y;
  const int rbase = blockIdx.x * 32;
  const float scale_r = 0.125f;  // 64^-0.5
  for (int l = tid; l < 512; l += 256) {
    int r = l >> 4, d4 = (l & 15) << 2;
    float4 qv = *(const float4*)&qr[(size_t)(rbase + r) * DR + h * DHR + d4];
    qv.x *= scale_r; qv.y *= scale_r; qv.z *= scale_r; qv.w *= scale_r;
    *(float4*)&Qs[r][d4] = qv;
  }
  if (tid < 32) { mL[tid] = -1e30f; lL[tid] = 0.f; }
  float o[2][4] = {};
  const int tmax = (rbase >> 3) + 3;
  const int ntiles = (tmax >> 6) + 1;
  for (int pt = 0; pt < ntiles; ++pt) {
    const int p0 = pt << 6;
    for (int l = tid; l < 1024; l += 256) {
      int c = l >> 4, d4 = (l & 15) << 2;
      *(float4*)&Ks[c][d4] = *(const float4*)&kr[(size_t)(p0 + c) * DR + h * DHR + d4];
      *(float4*)&Vs[c][d4] = *(const float4*)&vr[(size_t)(p0 + c) * DR + h * DHR + d4];
    }
    __syncthreads();
    float sc[2][4] = {};
#pragma unroll
    for (int d4 = 0; d4 < 64; d4 += 4) {
      float4 q0 = *(const float4*)&Qs[ty][d4];
      float4 q1 = *(const float4*)&Qs[ty + 16][d4];
#pragma unroll
      for (int j = 0; j < 4; ++j) {
        float4 kv = *(const float4*)&Ks[tx + 16 * j][d4];
        sc[0][j] += q0.x * kv.x + q0.y * kv.y + q0.z * kv.z + q0.w * kv.w;
        sc[1][j] += q1.x * kv.x + q1.y * kv.y + q1.z * kv.z + q1.w * kv.w;
      }
    }
#pragma unroll
    for (int i = 0; i < 2; ++i) {
      int trow = (rbase + ty + 16 * i) >> 3;
#pragma unroll
      for (int j = 0; j < 4; ++j) {
        int p = p0 + tx + 16 * j;
        Pt[tx + 16 * j][ty + 16 * i] = (p <= trow) ? sc[i][j] : -1e30f;
      }
    }
    __syncthreads();
    if (tid < 32) {
      const int r = tid;
      float mold = mL[r];
      float mx = mold;
      for (int c = 0; c < 64; ++c) mx = fmaxf(mx, Pt[c][r]);
      float sum = 0.f;
      for (int c = 0; c < 64; ++c) {
        float e = __expf(Pt[c][r] - mx);
        Pt[c][r] = e;
        sum += e;
      }
      float alpha = __expf(mold - mx);
      lL[r] = alpha * lL[r] + sum;
      mL[r] = mx;
      aL[r] = alpha;
    }
    __syncthreads();
#pragma unroll
    for (int i = 0; i < 2; ++i) {
      float al = aL[ty + 16 * i];
      o[i][0] *= al; o[i][1] *= al; o[i][2] *= al; o[i][3] *= al;
    }
    for (int c = 0; c < 64; ++c) {
      float4 vv = *(const float4*)&Vs[c][tx * 4];
      float pa = Pt[c][ty];
      float pb = Pt[c][ty + 16];
      o[0][0] += pa * vv.x; o[0][1] += pa * vv.y;
      o[0][2] += pa * vv.z; o[0][3] += pa * vv.w;
      o[1][0] += pb * vv.x; o[1][1] += pb * vv.y;
      o[1][2] += pb * vv.z; o[1][3] += pb * vv.w;
    }
    __syncthreads();
  }
#pragma unroll
  for (int i = 0; i < 2; ++i) {
    float inv = 1.f / lL[ty + 16 * i];
    __hip_bfloat16* out =
        &rat[(size_t)(rbase + ty + 16 * i) * DR + h * DHR + tx * 4];
    out[0] = __float2bfloat16(o[i][0] * inv);
    out[1] = __float2bfloat16(o[i][1] * inv);
    out[2] = __float2bfloat16(o[i][2] * inv);
    out[3] = __float2bfloat16(o[i][3] * inv);
  }
}

// ------------------------------------------------------------------- copy ---
__global__ __launch_bounds__(256) void copy4_kernel(const float4* __restrict__ in,
                                                    float4* __restrict__ out,
                                                    int n4) {
  int i = blockIdx.x * 256 + threadIdx.x;
  if (i < n4) out[i] = in[i];
}

// ----------------------------------------------------------------- launch ---
extern "C" void kernel_launch(void* const* d_in, const int* in_sizes, int n_in,
                              void* d_out, int out_size, void* d_ws,
                              size_t ws_size, hipStream_t stream) {
  const float* s   = (const float*)d_in[0];
  const float* r   = (const float*)d_in[1];
  const float* gv  = (const float*)d_in[2];
  const float* nsw = (const float*)d_in[3];
  const float* nrw = (const float*)d_in[4];
  const float* Wsq = (const float*)d_in[5];
  const float* Wsk = (const float*)d_in[6];
  const float* Wsv = (const float*)d_in[7];
  const float* Wso = (const float*)d_in[8];
  const float* Wrq = (const float*)d_in[9];
  const float* Wrk = (const float*)d_in[10];
  const float* Wrv = (const float*)d_in[11];
  const float* Wro = (const float*)d_in[12];

  float* outS = (float*)d_out;   // 1048576 fp32
  float* outR = outS + 1048576;  // 4194304 fp32

  // ---- workspace carve-up (107 MB total, proven budget) ----
  char* wp = (char*)d_ws;
  float* q  = (float*)wp;             wp += 1048576 * 4;  // 4 MB (doubles as s_n32)
  float* k  = (float*)wp;             wp += 8388608 * 4;  // 32 MB
  float* v  = (float*)wp;             wp += 8388608 * 4;  // 32 MB
  float* qr = (float*)wp;             wp += 4194304 * 4;  // 16 MB
  float* kr = (float*)wp;             wp += 524288 * 4;   // 2 MB
  float* vr = (float*)wp;             wp += 524288 * 4;   // 2 MB
  __hip_bfloat16* s_nb = (__hip_bfloat16*)wp; wp += 1048576 * 2;  // 2 MB
  __hip_bfloat16* r_nb = (__hip_bfloat16*)wp; wp += 4194304 * 2;  // 8 MB
  __hip_bfloat16* WsqT = (__hip_bfloat16*)wp; wp += 1048576 * 2;
  __hip_bfloat16* WskT = (__hip_bfloat16*)wp; wp += 524288 * 2;
  __hip_bfloat16* WsvT = (__hip_bfloat16*)wp; wp += 524288 * 2;
  __hip_bfloat16* WsoT = (__hip_bfloat16*)wp; wp += 1048576 * 2;
  __hip_bfloat16* WrqT = (__hip_bfloat16*)wp; wp += 262144 * 2;
  __hip_bfloat16* WrkT = (__hip_bfloat16*)wp; wp += 524288 * 2;
  __hip_bfloat16* WrvT = (__hip_bfloat16*)wp; wp += 524288 * 2;
  __hip_bfloat16* WroT = (__hip_bfloat16*)wp; wp += 262144 * 2;

  // Overlays (lifetime-checked against launch order below):
  float* s_n32 = q;                       // dead before q-gemm writes q
  float* Wc = (float*)r_nb;               // r_nb dead after k/v/qr gemms
  float* u  = (float*)((char*)r_nb + 2097152);
  __hip_bfloat16* attn1b = s_nb;          // s_nb dead after kr/vr gemms
  __hip_bfloat16* ratb   = r_nb;          // Wc,u dead after part1; flash is later

  // ---- weight transpose+cast to bf16 [N][K] ----
  transpose_bf16_kernel<<<dim3(32, 32), 256, 0, stream>>>(Wsq, WsqT, 1024, 1024);
  transpose_bf16_kernel<<<dim3(32, 16), 256, 0, stream>>>(Wsk, WskT, 512, 1024);
  transpose_bf16_kernel<<<dim3(32, 16), 256, 0, stream>>>(Wsv, WsvT, 512, 1024);
  transpose_bf16_kernel<<<dim3(32, 32), 256, 0, stream>>>(Wso, WsoT, 1024, 1024);
  transpose_bf16_kernel<<<dim3(16, 16), 256, 0, stream>>>(Wrq, WrqT, 512, 512);
  transpose_bf16_kernel<<<dim3(16, 32), 256, 0, stream>>>(Wrk, WrkT, 1024, 512);
  transpose_bf16_kernel<<<dim3(16, 32), 256, 0, stream>>>(Wrv, WrvT, 1024, 512);
  transpose_bf16_kernel<<<dim3(16, 16), 256, 0, stream>>>(Wro, WroT, 512, 512);

  // ---- RMS norms ----
  rmsnorm_bf16_kernel<<<1024, 256, 0, stream>>>(s, nsw, s_nb, s_n32, DS);
  rmsnorm_bf16_kernel<<<8192, 256, 0, stream>>>(r, nrw, r_nb, nullptr, DR);

  // ---- bf16 GEMMs consuming r_nb (must precede Wc/u overlay writes) ----
  mfma_gemm_kernel<false><<<dim3(8, 64), 256, 0, stream>>>(r_nb, WskT, k, 8192, 1024, 512);
  mfma_gemm_kernel<false><<<dim3(8, 64), 256, 0, stream>>>(r_nb, WsvT, v, 8192, 1024, 512);
  mfma_gemm_kernel<false><<<dim3(4, 64), 256, 0, stream>>>(r_nb, WrqT, qr, 8192, 512, 512);

  // ---- fp32 top-k score path: Wc = Wsq @ Wsk^T; u = s_n32 @ Wc ----
  gemm_f32_kernel<64, 4, false, true><<<dim3(8, 16), 256, 0, stream>>>(Wsq, Wsk, Wc, 1024, 512, 1024);
  gemm_f32_kernel<64, 4, false, false><<<dim3(8, 16), 256, 0, stream>>>(s_n32, Wc, u, 1024, 512, 1024);

  // ---- remaining bf16 GEMMs (q overwrites s_n32 — now dead) ----
  mfma_gemm_kernel<false><<<dim3(8, 8), 256, 0, stream>>>(s_nb, WsqT, q, 1024, 1024, 1024);
  mfma_gemm_kernel<false><<<dim3(4, 8), 256, 0, stream>>>(s_nb, WrkT, kr, 1024, 512, 1024);
  mfma_gemm_kernel<false><<<dim3(4, 8), 256, 0, stream>>>(s_nb, WrvT, vr, 1024, 512, 1024);

  // ---- part 1 + part 3 ----
  part1_kernel<<<1024, 256, 0, stream>>>(s, gv, q, k, v, r, nrw, u, attn1b, outS);
  mfma_gemm_kernel<true><<<dim3(8, 8), 256, 0, stream>>>(attn1b, WsoT, outS, 1024, 1024, 1024);

  // ---- part 2 ----
  copy4_kernel<<<4096, 256, 0, stream>>>((const float4*)r, (float4*)outR, 1048576);
  flash_kernel<<<dim3(256, 8), 256, 0, stream>>>(qr, kr, vr, ratb);
  mfma_gemm_kernel<true><<<dim3(4, 64), 256, 0, stream>>>(ratb, WroT, outR, 8192, 512, 512);
}

// Round 4
// 554.703 us; speedup vs baseline: 2.2951x; 1.7291x over previous
//
#include <hip/hip_runtime.h>
#include <hip/hip_bf16.h>
#include <math.h>
#include <type_traits>

// ---------------------------------------------------------------------------
// BridgeLayer: bf16-MFMA GEMMs + MFMA flash attention; fp32 top-k score path.
// Shapes: B=1, T=1024, N=8, H=8, D_S=1024 (DH_S=128), D_R=512 (DH_R=64), TOPK=4
// ---------------------------------------------------------------------------

#define T_DIM 1024
#define N_SLOT 8
#define DS 1024
#define DR 512
#define NH 8
#define DHS 128
#define DHR 64

typedef __attribute__((ext_vector_type(8))) short short8v;
typedef __attribute__((ext_vector_type(4))) float floatx4;

// ---------------------------------------------------------------- rmsnorm ---
__global__ __launch_bounds__(256) void rmsnorm_bf16_kernel(
    const float* __restrict__ x, const float* __restrict__ w,
    __hip_bfloat16* __restrict__ y, float* __restrict__ y32, int width) {
  const int row = blockIdx.x;
  const int tid = threadIdx.x;
  const size_t base = (size_t)row * width;
  float ss = 0.f;
  for (int i = tid; i < width; i += 256) {
    float v = x[base + i];
    ss += v * v;
  }
  for (int m = 32; m >= 1; m >>= 1) ss += __shfl_xor(ss, m);
  __shared__ float red[4];
  const int wave = tid >> 6, lane = tid & 63;
  if (lane == 0) red[wave] = ss;
  __syncthreads();
  float total = red[0] + red[1] + red[2] + red[3];
  float scale = rsqrtf(total / (float)width + 1e-6f);
  for (int i = tid; i < width; i += 256) {
    float val = x[base + i] * scale * w[i];
    y[base + i] = __float2bfloat16(val);
    if (y32) y32[base + i] = val;
  }
}

// -------------------------------------------------- weight transpose+cast ---
// Wt[n][k] = bf16(scale * W[k][n]).  grid = (N/32, K/32), block = 256.
__global__ __launch_bounds__(256) void transpose_bf16_kernel(
    const float* __restrict__ W, __hip_bfloat16* __restrict__ Wt, int K, int N,
    float scale) {
  __shared__ float t[32][33];
  const int tx = threadIdx.x & 31, ty = threadIdx.x >> 5;  // 32 x 8
  const int n0 = blockIdx.x * 32, k0 = blockIdx.y * 32;
#pragma unroll
  for (int i = 0; i < 4; ++i) {
    int kk = ty + i * 8;
    t[kk][tx] = W[(size_t)(k0 + kk) * N + n0 + tx];
  }
  __syncthreads();
#pragma unroll
  for (int i = 0; i < 4; ++i) {
    int nn = ty + i * 8;
    Wt[(size_t)(n0 + nn) * K + k0 + tx] = __float2bfloat16(t[tx][nn] * scale);
  }
}

// --------------------------------------------------------------- fp32 gemm --
// C[M,N] (+)= A[M,K] @ B.  BT=false: B is [K][N]; BT=true: B is [N][K] (NT).
template <int BS, int TT, bool ACCUM, bool BT>
__global__ __launch_bounds__(256) void gemm_f32_kernel(
    const float* __restrict__ A, const float* __restrict__ B,
    float* __restrict__ C, int M, int N, int K) {
  __shared__ __align__(16) float Ast[16][BS + 4];
  __shared__ __align__(16) float Bs[16][BS + 4];
  const int tid = threadIdx.x;
  const int tx = tid & 15, ty = tid >> 4;
  const int row0 = blockIdx.y * BS, col0 = blockIdx.x * BS;
  float acc[TT][TT] = {};
  constexpr int NF4 = BS * 16 / 4;
  for (int k0 = 0; k0 < K; k0 += 16) {
    __syncthreads();
    for (int l = tid; l < NF4; l += 256) {
      int lr = l >> 2, lk = (l & 3) << 2;
      float4 a4 = *(const float4*)&A[(size_t)(row0 + lr) * K + k0 + lk];
      Ast[lk + 0][lr] = a4.x;
      Ast[lk + 1][lr] = a4.y;
      Ast[lk + 2][lr] = a4.z;
      Ast[lk + 3][lr] = a4.w;
      if (BT) {
        float4 b4 = *(const float4*)&B[(size_t)(col0 + lr) * K + k0 + lk];
        Bs[lk + 0][lr] = b4.x;
        Bs[lk + 1][lr] = b4.y;
        Bs[lk + 2][lr] = b4.z;
        Bs[lk + 3][lr] = b4.w;
      } else {
        int bkk = l / (BS / 4), bc = (l % (BS / 4)) << 2;
        float4 b4 = *(const float4*)&B[(size_t)(k0 + bkk) * N + col0 + bc];
        *(float4*)&Bs[bkk][bc] = b4;
      }
    }
    __syncthreads();
#pragma unroll
    for (int kk = 0; kk < 16; ++kk) {
      float av[TT], bv[TT];
#pragma unroll
      for (int u = 0; u < TT; u += 4) {
        *(float4*)&av[u] = *(const float4*)&Ast[kk][ty * TT + u];
        *(float4*)&bv[u] = *(const float4*)&Bs[kk][tx * TT + u];
      }
#pragma unroll
      for (int i = 0; i < TT; ++i)
#pragma unroll
        for (int j = 0; j < TT; ++j) acc[i][j] += av[i] * bv[j];
    }
  }
#pragma unroll
  for (int i = 0; i < TT; ++i) {
    size_t crow = (size_t)(row0 + ty * TT + i) * N + col0;
#pragma unroll
    for (int j = 0; j < TT; j += 4) {
      float4 cv;
      if (ACCUM) {
        cv = *(const float4*)&C[crow + tx * TT + j];
        cv.x += acc[i][j + 0];
        cv.y += acc[i][j + 1];
        cv.z += acc[i][j + 2];
        cv.w += acc[i][j + 3];
      } else {
        cv = make_float4(acc[i][j], acc[i][j + 1], acc[i][j + 2], acc[i][j + 3]);
      }
      *(float4*)&C[crow + tx * TT + j] = cv;
    }
  }
}

// -------------------------------------------------------------- MFMA gemm ---
// C[M,N] (+)= A[M,K] @ Bt[N,K]^T.  A,Bt bf16 row-major; C fp32 or bf16.
template <bool ACCUM, typename OutT>
__global__ __launch_bounds__(256) void mfma_gemm_kernel(
    const __hip_bfloat16* __restrict__ A, const __hip_bfloat16* __restrict__ Bt,
    OutT* __restrict__ C, int M, int N, int K) {
  __shared__ __align__(16) __hip_bfloat16 As[128][40];
  __shared__ __align__(16) __hip_bfloat16 Bs[128][40];
  const int tid = threadIdx.x;
  const int lane = tid & 63, wave = tid >> 6;
  const int wm = wave >> 1, wn = wave & 1;
  const int l15 = lane & 15, l4 = lane >> 4;
  const int row0 = blockIdx.y * 128, col0 = blockIdx.x * 128;
  floatx4 acc[4][4] = {};
  for (int k0 = 0; k0 < K; k0 += 32) {
    __syncthreads();
#pragma unroll
    for (int g = tid; g < 512; g += 256) {
      int row = g >> 2, c = (g & 3) * 8;
      *(ulonglong2*)&As[row][c] =
          *(const ulonglong2*)&A[(size_t)(row0 + row) * K + k0 + c];
      *(ulonglong2*)&Bs[row][c] =
          *(const ulonglong2*)&Bt[(size_t)(col0 + row) * K + k0 + c];
    }
    __syncthreads();
    short8v af[4], bf[4];
#pragma unroll
    for (int i = 0; i < 4; ++i)
      af[i] = *(const short8v*)&As[wm * 64 + i * 16 + l15][l4 * 8];
#pragma unroll
    for (int j = 0; j < 4; ++j)
      bf[j] = *(const short8v*)&Bs[wn * 64 + j * 16 + l15][l4 * 8];
#pragma unroll
    for (int i = 0; i < 4; ++i)
#pragma unroll
      for (int j = 0; j < 4; ++j)
        acc[i][j] = __builtin_amdgcn_mfma_f32_16x16x32_bf16(af[i], bf[j],
                                                            acc[i][j], 0, 0, 0);
  }
  // C/D layout: col = lane&15, row = (lane>>4)*4 + reg  [m89-verified]
#pragma unroll
  for (int i = 0; i < 4; ++i) {
    int rb = row0 + wm * 64 + i * 16 + l4 * 4;
#pragma unroll
    for (int j = 0; j < 4; ++j) {
      int cb = col0 + wn * 64 + j * 16 + l15;
#pragma unroll
      for (int rg = 0; rg < 4; ++rg) {
        size_t idx = (size_t)(rb + rg) * N + cb;
        if constexpr (std::is_same<OutT, __hip_bfloat16>::value) {
          C[idx] = __float2bfloat16(acc[i][j][rg]);
        } else {
          if (ACCUM)
            C[idx] += acc[i][j][rg];
          else
            C[idx] = acc[i][j][rg];
        }
      }
    }
  }
}

// ---------------------------------------------- part1 + part3 (per t row) ---
__global__ __launch_bounds__(256) void part1_kernel(
    const float* __restrict__ s, const float* __restrict__ gv,
    const float* __restrict__ q, const float* __restrict__ k,
    const float* __restrict__ v, const float* __restrict__ r,
    const float* __restrict__ nrw, const float* __restrict__ u,
    __hip_bfloat16* __restrict__ attn1, float* __restrict__ outS) {
  __shared__ float qs[DS];
  __shared__ float dots[NH][N_SLOT];
  __shared__ float wattn[NH][N_SLOT];
  __shared__ float w8[N_SLOT];
  __shared__ float spv[N_SLOT];
  __shared__ float gateL;
  const int t = blockIdx.x;
  const int tid = threadIdx.x;
  for (int i = tid; i < DS; i += 256) qs[i] = q[(size_t)t * DS + i];
  __syncthreads();
  const int wave = tid >> 6, lane = tid & 63;
#pragma unroll
  for (int e = 0; e < 16; ++e) {
    int pair = wave * 16 + e;
    int h = pair >> 3, n = pair & 7;
    const float* krow = &k[((size_t)t * N_SLOT + n) * DS + h * DHS];
    float a = qs[h * DHS + lane] * krow[lane] +
              qs[h * DHS + 64 + lane] * krow[64 + lane];
    for (int m = 32; m >= 1; m >>= 1) a += __shfl_xor(a, m);
    if (lane == 0) dots[h][n] = a;
  }
  const float scale_s = 0.08838834764831845f;  // 128^-0.5
  // fp32 sp: wave w handles slots 2w, 2w+1
#pragma unroll
  for (int e = 0; e < 2; ++e) {
    const int n = wave * 2 + e;
    const float* rr = &r[((size_t)t * N_SLOT + n) * DR];
    const float* ub = &u[(size_t)t * DR];
    float ssum = 0.f, dot = 0.f;
#pragma unroll
    for (int jj = 0; jj < 8; ++jj) {
      int j = lane + 64 * jj;
      float rv = rr[j];
      ssum += rv * rv;
      dot += rv * nrw[j] * ub[j];
    }
    for (int m = 32; m >= 1; m >>= 1) {
      ssum += __shfl_xor(ssum, m);
      dot += __shfl_xor(dot, m);
    }
    if (lane == 0) {
      float rs = rsqrtf(ssum / (float)DR + 1e-6f);
      spv[n] = scale_s * rs * dot;
    }
  }
  __syncthreads();
  if (tid < 8) {
    int h = tid;
    float vmax = -1e30f;
    for (int n = 0; n < 8; ++n) vmax = fmaxf(vmax, dots[h][n] * scale_s);
    float sum = 0.f;
    for (int n = 0; n < 8; ++n) {
      float e = __expf(dots[h][n] * scale_s - vmax);
      wattn[h][n] = e;
      sum += e;
    }
    float inv = 1.f / sum;
    for (int n = 0; n < 8; ++n) wattn[h][n] *= inv;
  }
  if (tid == 64) {
    float sv[8];
    for (int n = 0; n < 8; ++n) sv[n] = spv[n];
    bool used[8] = {};
    float vals[4];
    int idxs[4];
    for (int kk = 0; kk < 4; ++kk) {
      float best = -1e30f;
      int bi = 0;
      for (int n = 0; n < 8; ++n)
        if (!used[n] && sv[n] > best) { best = sv[n]; bi = n; }
      used[bi] = true;
      vals[kk] = best;
      idxs[kk] = bi;
    }
    float mx = vals[0];
    float wv[4];
    float sum = 0.f;
    for (int kk = 0; kk < 4; ++kk) {
      wv[kk] = __expf(vals[kk] - mx);
      sum += wv[kk];
    }
    float inv = 1.f / sum;
    for (int n = 0; n < 8; ++n) w8[n] = 0.f;
    for (int kk = 0; kk < 4; ++kk) w8[idxs[kk]] = wv[kk] * inv;
    gateL = gv[t];
  }
  __syncthreads();
  const float gate = gateL;
#pragma unroll
  for (int jj = 0; jj < 4; ++jj) {
    int d = tid + 256 * jj;
    int hh = d >> 7;
    float a1 = 0.f, a2 = 0.f;
#pragma unroll
    for (int n = 0; n < 8; ++n) {
      float vv = v[((size_t)t * N_SLOT + n) * DS + d];
      a1 += wattn[hh][n] * vv;
      a2 += w8[n] * vv;
    }
    attn1[(size_t)t * DS + d] = __float2bfloat16(a1);
    outS[(size_t)t * DS + d] = s[(size_t)t * DS + d] + gate * a2;
  }
}

// ------------------------------------------- part2 MFMA flash attention -----
// qb: [8192][512] bf16 pre-scaled by 2^-3 (folded into WrqT); kb/vb: [1024][512].
// Grid (128 q-tiles of 64 rows, 8 heads), 4 waves; wave owns 16-row strip.
// Online softmax fully register-resident (rows live in 16-lane groups).
__global__ __launch_bounds__(256) void flash_mfma_kernel(
    const __hip_bfloat16* __restrict__ qb, const __hip_bfloat16* __restrict__ kb,
    const __hip_bfloat16* __restrict__ vb, __hip_bfloat16* __restrict__ rat) {
  __shared__ __align__(16) __hip_bfloat16 Qs[64][72];
  __shared__ __align__(16) __hip_bfloat16 Ks[64][72];
  __shared__ __align__(16) __hip_bfloat16 Vt[64][72];  // [dim][key]
  __shared__ __align__(16) __hip_bfloat16 Pb[64][72];  // [qrow][key] wave-local
  const int tid = threadIdx.x;
  const int lane = tid & 63, wave = tid >> 6;
  const int l15 = lane & 15, l4 = lane >> 4;
  const int h = blockIdx.y;
  const int qbase = blockIdx.x * 64;
  const int t0 = qbase >> 3;  // min t in tile (t = row>>3)

  for (int g = tid; g < 512; g += 256) {
    int rr = g >> 3, c = (g & 7) * 8;
    *(ulonglong2*)&Qs[rr][c] =
        *(const ulonglong2*)&qb[(size_t)(qbase + rr) * DR + h * DHR + c];
  }
  __syncthreads();
  short8v qf[2];
#pragma unroll
  for (int kk = 0; kk < 2; ++kk)
    qf[kk] = *(const short8v*)&Qs[wave * 16 + l15][kk * 32 + l4 * 8];

  float m_row[4], l_row[4];
#pragma unroll
  for (int rg = 0; rg < 4; ++rg) { m_row[rg] = -1e30f; l_row[rg] = 0.f; }
  floatx4 o_acc[4] = {};  // C layout: col = 16*jd + l15 (dim), row = l4*4+reg

  const int ntiles = ((t0 + 7) >> 6) + 1;
  for (int pt = 0; pt < ntiles; ++pt) {
    const int p0 = pt << 6;
    __syncthreads();  // protect Ks/Vt from previous iteration's readers
    for (int g = tid; g < 512; g += 256) {
      int rr = g >> 3, c = (g & 7) * 8;
      *(ulonglong2*)&Ks[rr][c] =
          *(const ulonglong2*)&kb[(size_t)(p0 + rr) * DR + h * DHR + c];
      __hip_bfloat16 vtmp[8];
      *(ulonglong2*)vtmp =
          *(const ulonglong2*)&vb[(size_t)(p0 + rr) * DR + h * DHR + c];
#pragma unroll
      for (int j = 0; j < 8; ++j) Vt[c + j][rr] = vtmp[j];
    }
    __syncthreads();
    // S = Q @ K^T for this wave's 16-row strip (4 key subtiles)
    floatx4 sc[4] = {};
#pragma unroll
    for (int j = 0; j < 4; ++j)
#pragma unroll
      for (int kk = 0; kk < 2; ++kk) {
        short8v kf = *(const short8v*)&Ks[j * 16 + l15][kk * 32 + l4 * 8];
        sc[j] = __builtin_amdgcn_mfma_f32_16x16x32_bf16(qf[kk], kf, sc[j], 0, 0, 0);
      }
    const bool boundary = (p0 + 63 > t0);
    float mnew[4], alpha[4];
#pragma unroll
    for (int rg = 0; rg < 4; ++rg) {
      const int t = (qbase + wave * 16 + l4 * 4 + rg) >> 3;
      float mx = m_row[rg];
#pragma unroll
      for (int j = 0; j < 4; ++j) {
        float vsc = sc[j][rg];
        if (boundary && (p0 + j * 16 + l15) > t) vsc = -1e30f;
        sc[j][rg] = vsc;
        mx = fmaxf(mx, vsc);
      }
      for (int mm = 1; mm < 16; mm <<= 1) mx = fmaxf(mx, __shfl_xor(mx, mm));
      mnew[rg] = mx;
    }
#pragma unroll
    for (int rg = 0; rg < 4; ++rg) {
      float sum = 0.f;
#pragma unroll
      for (int j = 0; j < 4; ++j) {
        float e = __expf(sc[j][rg] - mnew[rg]);
        sc[j][rg] = e;
        sum += e;
      }
      for (int mm = 1; mm < 16; mm <<= 1) sum += __shfl_xor(sum, mm);
      alpha[rg] = __expf(m_row[rg] - mnew[rg]);
      l_row[rg] = alpha[rg] * l_row[rg] + sum;
      m_row[rg] = mnew[rg];
    }
    // P -> LDS (bf16); rows are wave-local so no barrier needed
#pragma unroll
    for (int j = 0; j < 4; ++j)
#pragma unroll
      for (int rg = 0; rg < 4; ++rg)
        Pb[wave * 16 + l4 * 4 + rg][j * 16 + l15] = __float2bfloat16(sc[j][rg]);
#pragma unroll
    for (int jd = 0; jd < 4; ++jd)
#pragma unroll
      for (int rg = 0; rg < 4; ++rg) o_acc[jd][rg] *= alpha[rg];
    // O += P @ V   (A = P rows, B = Vt rows = output dims)
#pragma unroll
    for (int kk = 0; kk < 2; ++kk) {
      short8v pf = *(const short8v*)&Pb[wave * 16 + l15][kk * 32 + l4 * 8];
#pragma unroll
      for (int jd = 0; jd < 4; ++jd) {
        short8v vf = *(const short8v*)&Vt[jd * 16 + l15][kk * 32 + l4 * 8];
        o_acc[jd] = __builtin_amdgcn_mfma_f32_16x16x32_bf16(pf, vf, o_acc[jd], 0, 0, 0);
      }
    }
  }
#pragma unroll
  for (int rg = 0; rg < 4; ++rg) {
    float inv = 1.f / l_row[rg];
    int row = qbase + wave * 16 + l4 * 4 + rg;
#pragma unroll
    for (int jd = 0; jd < 4; ++jd)
      rat[(size_t)row * DR + h * DHR + jd * 16 + l15] =
          __float2bfloat16(o_acc[jd][rg] * inv);
  }
}

// ------------------------------------------------------------------- copy ---
__global__ __launch_bounds__(256) void copy4_kernel(const float4* __restrict__ in,
                                                    float4* __restrict__ out,
                                                    int n4) {
  int i = blockIdx.x * 256 + threadIdx.x;
  if (i < n4) out[i] = in[i];
}

// ----------------------------------------------------------------- launch ---
extern "C" void kernel_launch(void* const* d_in, const int* in_sizes, int n_in,
                              void* d_out, int out_size, void* d_ws,
                              size_t ws_size, hipStream_t stream) {
  const float* s   = (const float*)d_in[0];
  const float* r   = (const float*)d_in[1];
  const float* gv  = (const float*)d_in[2];
  const float* nsw = (const float*)d_in[3];
  const float* nrw = (const float*)d_in[4];
  const float* Wsq = (const float*)d_in[5];
  const float* Wsk = (const float*)d_in[6];
  const float* Wsv = (const float*)d_in[7];
  const float* Wso = (const float*)d_in[8];
  const float* Wrq = (const float*)d_in[9];
  const float* Wrk = (const float*)d_in[10];
  const float* Wrv = (const float*)d_in[11];
  const float* Wro = (const float*)d_in[12];

  float* outS = (float*)d_out;   // 1048576 fp32
  float* outR = outS + 1048576;  // 4194304 fp32

  // ---- workspace carve-up (~97 MB, under proven 108 MB budget) ----
  char* wp = (char*)d_ws;
  float* q  = (float*)wp;             wp += 1048576 * 4;  // 4 MB (doubles as s_n32)
  float* k  = (float*)wp;             wp += 8388608 * 4;  // 32 MB
  float* v  = (float*)wp;             wp += 8388608 * 4;  // 32 MB
  __hip_bfloat16* qrb = (__hip_bfloat16*)wp; wp += 4194304 * 2;  // 8 MB
  __hip_bfloat16* krb = (__hip_bfloat16*)wp; wp += 524288 * 2;   // 1 MB
  __hip_bfloat16* vrb = (__hip_bfloat16*)wp; wp += 524288 * 2;   // 1 MB
  __hip_bfloat16* s_nb = (__hip_bfloat16*)wp; wp += 1048576 * 2; // 2 MB
  __hip_bfloat16* r_nb = (__hip_bfloat16*)wp; wp += 4194304 * 2; // 8 MB
  __hip_bfloat16* WsqT = (__hip_bfloat16*)wp; wp += 1048576 * 2;
  __hip_bfloat16* WskT = (__hip_bfloat16*)wp; wp += 524288 * 2;
  __hip_bfloat16* WsvT = (__hip_bfloat16*)wp; wp += 524288 * 2;
  __hip_bfloat16* WsoT = (__hip_bfloat16*)wp; wp += 1048576 * 2;
  __hip_bfloat16* WrqT = (__hip_bfloat16*)wp; wp += 262144 * 2;
  __hip_bfloat16* WrkT = (__hip_bfloat16*)wp; wp += 524288 * 2;
  __hip_bfloat16* WrvT = (__hip_bfloat16*)wp; wp += 524288 * 2;
  __hip_bfloat16* WroT = (__hip_bfloat16*)wp; wp += 262144 * 2;

  // Overlays (lifetime-checked against launch order below):
  float* s_n32 = q;                       // dead before q-gemm writes q
  float* Wc = (float*)r_nb;               // r_nb dead after k/v/qr gemms
  float* u  = (float*)((char*)r_nb + 2097152);
  __hip_bfloat16* attn1b = s_nb;          // s_nb dead after kr/vr gemms
  __hip_bfloat16* ratb   = r_nb;          // Wc,u dead after part1; flash later

  // ---- weight transpose+cast to bf16 [N][K]; Wrq pre-scaled by 2^-3 ----
  transpose_bf16_kernel<<<dim3(32, 32), 256, 0, stream>>>(Wsq, WsqT, 1024, 1024, 1.f);
  transpose_bf16_kernel<<<dim3(32, 16), 256, 0, stream>>>(Wsk, WskT, 512, 1024, 1.f);
  transpose_bf16_kernel<<<dim3(32, 16), 256, 0, stream>>>(Wsv, WsvT, 512, 1024, 1.f);
  transpose_bf16_kernel<<<dim3(32, 32), 256, 0, stream>>>(Wso, WsoT, 1024, 1024, 1.f);
  transpose_bf16_kernel<<<dim3(16, 16), 256, 0, stream>>>(Wrq, WrqT, 512, 512, 0.125f);
  transpose_bf16_kernel<<<dim3(16, 32), 256, 0, stream>>>(Wrk, WrkT, 1024, 512, 1.f);
  transpose_bf16_kernel<<<dim3(16, 32), 256, 0, stream>>>(Wrv, WrvT, 1024, 512, 1.f);
  transpose_bf16_kernel<<<dim3(16, 16), 256, 0, stream>>>(Wro, WroT, 512, 512, 1.f);

  // ---- RMS norms ----
  rmsnorm_bf16_kernel<<<1024, 256, 0, stream>>>(s, nsw, s_nb, s_n32, DS);
  rmsnorm_bf16_kernel<<<8192, 256, 0, stream>>>(r, nrw, r_nb, nullptr, DR);

  // ---- bf16 GEMMs consuming r_nb (must precede Wc/u overlay writes) ----
  mfma_gemm_kernel<false, float><<<dim3(8, 64), 256, 0, stream>>>(r_nb, WskT, k, 8192, 1024, 512);
  mfma_gemm_kernel<false, float><<<dim3(8, 64), 256, 0, stream>>>(r_nb, WsvT, v, 8192, 1024, 512);
  mfma_gemm_kernel<false, __hip_bfloat16><<<dim3(4, 64), 256, 0, stream>>>(r_nb, WrqT, qrb, 8192, 512, 512);

  // ---- fp32 top-k score path: Wc = Wsq @ Wsk^T; u = s_n32 @ Wc ----
  gemm_f32_kernel<64, 4, false, true><<<dim3(8, 16), 256, 0, stream>>>(Wsq, Wsk, Wc, 1024, 512, 1024);
  gemm_f32_kernel<64, 4, false, false><<<dim3(8, 16), 256, 0, stream>>>(s_n32, Wc, u, 1024, 512, 1024);

  // ---- remaining bf16 GEMMs (q overwrites s_n32 — now dead) ----
  mfma_gemm_kernel<false, float><<<dim3(8, 8), 256, 0, stream>>>(s_nb, WsqT, q, 1024, 1024, 1024);
  mfma_gemm_kernel<false, __hip_bfloat16><<<dim3(4, 8), 256, 0, stream>>>(s_nb, WrkT, krb, 1024, 512, 1024);
  mfma_gemm_kernel<false, __hip_bfloat16><<<dim3(4, 8), 256, 0, stream>>>(s_nb, WrvT, vrb, 1024, 512, 1024);

  // ---- part 1 + part 3 ----
  part1_kernel<<<1024, 256, 0, stream>>>(s, gv, q, k, v, r, nrw, u, attn1b, outS);
  mfma_gemm_kernel<true, float><<<dim3(8, 8), 256, 0, stream>>>(attn1b, WsoT, outS, 1024, 1024, 1024);

  // ---- part 2 ----
  copy4_kernel<<<4096, 256, 0, stream>>>((const float4*)r, (float4*)outR, 1048576);
  flash_mfma_kernel<<<dim3(128, 8), 256, 0, stream>>>(qrb, krb, vrb, ratb);
  mfma_gemm_kernel<true, float><<<dim3(4, 64), 256, 0, stream>>>(ratb, WroT, outR, 8192, 512, 512);
}

// Round 6
// 527.055 us; speedup vs baseline: 2.4155x; 1.0525x over previous
//
#include <hip/hip_runtime.h>
#include <hip/hip_bf16.h>
#include <math.h>
#include <type_traits>

// ---------------------------------------------------------------------------
// BridgeLayer: bf16-MFMA GEMMs + MFMA flash attention; fp32 top-k score path.
// Shapes: B=1, T=1024, N=8, H=8, D_S=1024 (DH_S=128), D_R=512 (DH_R=64), TOPK=4
// ---------------------------------------------------------------------------

#define T_DIM 1024
#define N_SLOT 8
#define DS 1024
#define DR 512
#define NH 8
#define DHS 128
#define DHR 64

typedef __attribute__((ext_vector_type(8))) short short8v;
typedef __attribute__((ext_vector_type(4))) float floatx4;

// ---------------------------------------------------------------- rmsnorm ---
__global__ __launch_bounds__(256) void rmsnorm_bf16_kernel(
    const float* __restrict__ x, const float* __restrict__ w,
    __hip_bfloat16* __restrict__ y, float* __restrict__ y32, int width) {
  const int row = blockIdx.x;
  const int tid = threadIdx.x;
  const size_t base = (size_t)row * width;
  float ss = 0.f;
  for (int i = tid; i < width; i += 256) {
    float v = x[base + i];
    ss += v * v;
  }
  for (int m = 32; m >= 1; m >>= 1) ss += __shfl_xor(ss, m);
  __shared__ float red[4];
  const int wave = tid >> 6, lane = tid & 63;
  if (lane == 0) red[wave] = ss;
  __syncthreads();
  float total = red[0] + red[1] + red[2] + red[3];
  float scale = rsqrtf(total / (float)width + 1e-6f);
  for (int i = tid; i < width; i += 256) {
    float val = x[base + i] * scale * w[i];
    y[base + i] = __float2bfloat16(val);
    if (y32) y32[base + i] = val;
  }
}

// -------------------------------------------------- weight transpose+cast ---
__global__ __launch_bounds__(256) void transpose_bf16_kernel(
    const float* __restrict__ W, __hip_bfloat16* __restrict__ Wt, int K, int N,
    float scale) {
  __shared__ float t[32][33];
  const int tx = threadIdx.x & 31, ty = threadIdx.x >> 5;  // 32 x 8
  const int n0 = blockIdx.x * 32, k0 = blockIdx.y * 32;
#pragma unroll
  for (int i = 0; i < 4; ++i) {
    int kk = ty + i * 8;
    t[kk][tx] = W[(size_t)(k0 + kk) * N + n0 + tx];
  }
  __syncthreads();
#pragma unroll
  for (int i = 0; i < 4; ++i) {
    int nn = ty + i * 8;
    Wt[(size_t)(n0 + nn) * K + k0 + tx] = __float2bfloat16(t[tx][nn] * scale);
  }
}

// --------------------------------------------------------------- fp32 gemm --
// C[M,N] = A[M,K] @ B.  BT=false: B is [K][N]; BT=true: B is [N][K] (NT).
template <int BS, int TT, bool BT>
__global__ __launch_bounds__(256) void gemm_f32_kernel(
    const float* __restrict__ A, const float* __restrict__ B,
    float* __restrict__ C, int M, int N, int K) {
  __shared__ __align__(16) float Ast[16][BS + 4];
  __shared__ __align__(16) float Bs[16][BS + 4];
  const int tid = threadIdx.x;
  const int tx = tid & 15, ty = tid >> 4;
  const int row0 = blockIdx.y * BS, col0 = blockIdx.x * BS;
  float acc[TT][TT] = {};
  constexpr int NF4 = BS * 16 / 4;
  for (int k0 = 0; k0 < K; k0 += 16) {
    __syncthreads();
    for (int l = tid; l < NF4; l += 256) {
      int lr = l >> 2, lk = (l & 3) << 2;
      float4 a4 = *(const float4*)&A[(size_t)(row0 + lr) * K + k0 + lk];
      Ast[lk + 0][lr] = a4.x;
      Ast[lk + 1][lr] = a4.y;
      Ast[lk + 2][lr] = a4.z;
      Ast[lk + 3][lr] = a4.w;
      if (BT) {
        float4 b4 = *(const float4*)&B[(size_t)(col0 + lr) * K + k0 + lk];
        Bs[lk + 0][lr] = b4.x;
        Bs[lk + 1][lr] = b4.y;
        Bs[lk + 2][lr] = b4.z;
        Bs[lk + 3][lr] = b4.w;
      } else {
        int bkk = l / (BS / 4), bc = (l % (BS / 4)) << 2;
        float4 b4 = *(const float4*)&B[(size_t)(k0 + bkk) * N + col0 + bc];
        *(float4*)&Bs[bkk][bc] = b4;
      }
    }
    __syncthreads();
#pragma unroll
    for (int kk = 0; kk < 16; ++kk) {
      float av[TT], bv[TT];
#pragma unroll
      for (int u = 0; u < TT; u += 4) {
        *(float4*)&av[u] = *(const float4*)&Ast[kk][ty * TT + u];
        *(float4*)&bv[u] = *(const float4*)&Bs[kk][tx * TT + u];
      }
#pragma unroll
      for (int i = 0; i < TT; ++i)
#pragma unroll
        for (int j = 0; j < TT; ++j) acc[i][j] += av[i] * bv[j];
    }
  }
#pragma unroll
  for (int i = 0; i < TT; ++i) {
    size_t crow = (size_t)(row0 + ty * TT + i) * N + col0;
#pragma unroll
    for (int j = 0; j < TT; j += 4) {
      *(float4*)&C[crow + tx * TT + j] =
          make_float4(acc[i][j], acc[i][j + 1], acc[i][j + 2], acc[i][j + 3]);
    }
  }
}

// -------------------------------------------------------------- MFMA gemm ---
// C (+)= A[M,K] @ Bt[N,K]^T.  A,Bt bf16 row-major; OutT fp32 or bf16.
// TRANS: write C transposed, CT[n][m] (bf16 only; used for flash V^T).
template <bool ACCUM, typename OutT, bool TRANS = false>
__global__ __launch_bounds__(256) void mfma_gemm_kernel(
    const __hip_bfloat16* __restrict__ A, const __hip_bfloat16* __restrict__ Bt,
    OutT* __restrict__ C, int M, int N, int K) {
  __shared__ __align__(16) __hip_bfloat16 As[128][40];
  __shared__ __align__(16) __hip_bfloat16 Bs[128][40];
  const int tid = threadIdx.x;
  const int lane = tid & 63, wave = tid >> 6;
  const int wm = wave >> 1, wn = wave & 1;
  const int l15 = lane & 15, l4 = lane >> 4;
  const int row0 = blockIdx.y * 128, col0 = blockIdx.x * 128;
  floatx4 acc[4][4] = {};
  for (int k0 = 0; k0 < K; k0 += 32) {
    __syncthreads();
#pragma unroll
    for (int g = tid; g < 512; g += 256) {
      int row = g >> 2, c = (g & 3) * 8;
      *(ulonglong2*)&As[row][c] =
          *(const ulonglong2*)&A[(size_t)(row0 + row) * K + k0 + c];
      *(ulonglong2*)&Bs[row][c] =
          *(const ulonglong2*)&Bt[(size_t)(col0 + row) * K + k0 + c];
    }
    __syncthreads();
    short8v af[4], bf[4];
#pragma unroll
    for (int i = 0; i < 4; ++i)
      af[i] = *(const short8v*)&As[wm * 64 + i * 16 + l15][l4 * 8];
#pragma unroll
    for (int j = 0; j < 4; ++j)
      bf[j] = *(const short8v*)&Bs[wn * 64 + j * 16 + l15][l4 * 8];
#pragma unroll
    for (int i = 0; i < 4; ++i)
#pragma unroll
      for (int j = 0; j < 4; ++j)
        acc[i][j] = __builtin_amdgcn_mfma_f32_16x16x32_bf16(af[i], bf[j],
                                                            acc[i][j], 0, 0, 0);
  }
  // C/D layout: col = lane&15, row = (lane>>4)*4 + reg  [m89-verified]
#pragma unroll
  for (int i = 0; i < 4; ++i) {
    int rb = row0 + wm * 64 + i * 16 + l4 * 4;
#pragma unroll
    for (int j = 0; j < 4; ++j) {
      int cb = col0 + wn * 64 + j * 16 + l15;
      if constexpr (TRANS) {
        // CT[cb][rb..rb+3], 4 contiguous bf16 = one 8B store
        __hip_bfloat16 pk[4];
#pragma unroll
        for (int rg = 0; rg < 4; ++rg) pk[rg] = __float2bfloat16(acc[i][j][rg]);
        *(ushort4*)&C[(size_t)cb * M + rb] = *(const ushort4*)pk;
      } else {
#pragma unroll
        for (int rg = 0; rg < 4; ++rg) {
          size_t idx = (size_t)(rb + rg) * N + cb;
          if constexpr (std::is_same<OutT, __hip_bfloat16>::value) {
            C[idx] = __float2bfloat16(acc[i][j][rg]);
          } else {
            if (ACCUM)
              C[idx] += acc[i][j][rg];
            else
              C[idx] = acc[i][j][rg];
          }
        }
      }
    }
  }
}

// ---------------------------------------------- part1 + part3 (per t row) ---
// q,k,v bf16 (continuous paths); top-k via fp32 r·u path.
__global__ __launch_bounds__(256) void part1_kernel(
    const float* __restrict__ s, const float* __restrict__ gv,
    const __hip_bfloat16* __restrict__ q, const __hip_bfloat16* __restrict__ k,
    const __hip_bfloat16* __restrict__ v, const float* __restrict__ r,
    const float* __restrict__ nrw, const float* __restrict__ u,
    __hip_bfloat16* __restrict__ attn1, float* __restrict__ outS) {
  __shared__ float qs[DS];
  __shared__ float dots[NH][N_SLOT];
  __shared__ float wattn[NH][N_SLOT];
  __shared__ float w8[N_SLOT];
  __shared__ float spv[N_SLOT];
  __shared__ float gateL;
  const int t = blockIdx.x;
  const int tid = threadIdx.x;
  for (int i = tid; i < DS; i += 256) qs[i] = __bfloat162float(q[(size_t)t * DS + i]);
  __syncthreads();
  const int wave = tid >> 6, lane = tid & 63;
#pragma unroll
  for (int e = 0; e < 16; ++e) {
    int pair = wave * 16 + e;
    int h = pair >> 3, n = pair & 7;
    const __hip_bfloat16* krow = &k[((size_t)t * N_SLOT + n) * DS + h * DHS];
    float a = qs[h * DHS + lane] * __bfloat162float(krow[lane]) +
              qs[h * DHS + 64 + lane] * __bfloat162float(krow[64 + lane]);
    for (int m = 32; m >= 1; m >>= 1) a += __shfl_xor(a, m);
    if (lane == 0) dots[h][n] = a;
  }
  const float scale_s = 0.08838834764831845f;  // 128^-0.5
  // fp32 sp: wave w handles slots 2w, 2w+1
#pragma unroll
  for (int e = 0; e < 2; ++e) {
    const int n = wave * 2 + e;
    const float* rr = &r[((size_t)t * N_SLOT + n) * DR];
    const float* ub = &u[(size_t)t * DR];
    float ssum = 0.f, dot = 0.f;
#pragma unroll
    for (int jj = 0; jj < 8; ++jj) {
      int j = lane + 64 * jj;
      float rv = rr[j];
      ssum += rv * rv;
      dot += rv * nrw[j] * ub[j];
    }
    for (int m = 32; m >= 1; m >>= 1) {
      ssum += __shfl_xor(ssum, m);
      dot += __shfl_xor(dot, m);
    }
    if (lane == 0) {
      float rs = rsqrtf(ssum / (float)DR + 1e-6f);
      spv[n] = scale_s * rs * dot;
    }
  }
  __syncthreads();
  if (tid < 8) {
    int h = tid;
    float vmax = -1e30f;
    for (int n = 0; n < 8; ++n) vmax = fmaxf(vmax, dots[h][n] * scale_s);
    float sum = 0.f;
    for (int n = 0; n < 8; ++n) {
      float e = __expf(dots[h][n] * scale_s - vmax);
      wattn[h][n] = e;
      sum += e;
    }
    float inv = 1.f / sum;
    for (int n = 0; n < 8; ++n) wattn[h][n] *= inv;
  }
  if (tid == 64) {
    float sv[8];
    for (int n = 0; n < 8; ++n) sv[n] = spv[n];
    bool used[8] = {};
    float vals[4];
    int idxs[4];
    for (int kk = 0; kk < 4; ++kk) {
      float best = -1e30f;
      int bi = 0;
      for (int n = 0; n < 8; ++n)
        if (!used[n] && sv[n] > best) { best = sv[n]; bi = n; }
      used[bi] = true;
      vals[kk] = best;
      idxs[kk] = bi;
    }
    float mx = vals[0];
    float wv[4];
    float sum = 0.f;
    for (int kk = 0; kk < 4; ++kk) {
      wv[kk] = __expf(vals[kk] - mx);
      sum += wv[kk];
    }
    float inv = 1.f / sum;
    for (int n = 0; n < 8; ++n) w8[n] = 0.f;
    for (int kk = 0; kk < 4; ++kk) w8[idxs[kk]] = wv[kk] * inv;
    gateL = gv[t];
  }
  __syncthreads();
  const float gate = gateL;
#pragma unroll
  for (int jj = 0; jj < 4; ++jj) {
    int d = tid + 256 * jj;
    int hh = d >> 7;
    float a1 = 0.f, a2 = 0.f;
#pragma unroll
    for (int n = 0; n < 8; ++n) {
      float vv = __bfloat162float(v[((size_t)t * N_SLOT + n) * DS + d]);
      a1 += wattn[hh][n] * vv;
      a2 += w8[n] * vv;
    }
    attn1[(size_t)t * DS + d] = __float2bfloat16(a1);
    outS[(size_t)t * DS + d] = s[(size_t)t * DS + d] + gate * a2;
  }
}

// ------------------------------------------- part2 MFMA flash attention -----
// qb: [8192][512] bf16 pre-scaled by 2^-3; kb: [1024][512]; vbT: [512][1024]
// (pre-transposed by the Wrv GEMM). Grid (128 q-tiles x 64 rows, 8 heads),
// 4 waves; wave owns a 16-row strip; online softmax register-resident.
__global__ __launch_bounds__(256) void flash_mfma_kernel(
    const __hip_bfloat16* __restrict__ qb, const __hip_bfloat16* __restrict__ kb,
    const __hip_bfloat16* __restrict__ vbT, __hip_bfloat16* __restrict__ rat) {
  __shared__ __align__(16) __hip_bfloat16 Qs[64][72];
  __shared__ __align__(16) __hip_bfloat16 Ks[64][72];
  __shared__ __align__(16) __hip_bfloat16 Vt[64][72];  // [dim][key]
  __shared__ __align__(16) __hip_bfloat16 Pb[64][72];  // [qrow][key] wave-local
  const int tid = threadIdx.x;
  const int lane = tid & 63, wave = tid >> 6;
  const int l15 = lane & 15, l4 = lane >> 4;
  const int h = blockIdx.y;
  const int qbase = blockIdx.x * 64;
  const int t0 = qbase >> 3;  // min t in tile (t = row>>3)

  for (int g = tid; g < 512; g += 256) {
    int rr = g >> 3, c = (g & 7) * 8;
    *(ulonglong2*)&Qs[rr][c] =
        *(const ulonglong2*)&qb[(size_t)(qbase + rr) * DR + h * DHR + c];
  }
  __syncthreads();
  short8v qf[2];
#pragma unroll
  for (int kk = 0; kk < 2; ++kk)
    qf[kk] = *(const short8v*)&Qs[wave * 16 + l15][kk * 32 + l4 * 8];

  float m_row[4], l_row[4];
#pragma unroll
  for (int rg = 0; rg < 4; ++rg) { m_row[rg] = -1e30f; l_row[rg] = 0.f; }
  floatx4 o_acc[4] = {};  // C layout: col = 16*jd + l15 (dim), row = l4*4+reg

  const int ntiles = ((t0 + 7) >> 6) + 1;
  for (int pt = 0; pt < ntiles; ++pt) {
    const int p0 = pt << 6;
    __syncthreads();  // protect Ks/Vt from previous iteration's readers
    for (int g = tid; g < 512; g += 256) {
      int rr = g >> 3, c = (g & 7) * 8;
      *(ulonglong2*)&Ks[rr][c] =
          *(const ulonglong2*)&kb[(size_t)(p0 + rr) * DR + h * DHR + c];
      // Vt rows = head dims, cols = keys; vbT row pitch = T_DIM
      *(ulonglong2*)&Vt[rr][c] =
          *(const ulonglong2*)&vbT[(size_t)(h * DHR + rr) * T_DIM + p0 + c];
    }
    __syncthreads();
    // S = Q @ K^T for this wave's 16-row strip (4 key subtiles)
    floatx4 sc[4] = {};
#pragma unroll
    for (int j = 0; j < 4; ++j)
#pragma unroll
      for (int kk = 0; kk < 2; ++kk) {
        short8v kf = *(const short8v*)&Ks[j * 16 + l15][kk * 32 + l4 * 8];
        sc[j] = __builtin_amdgcn_mfma_f32_16x16x32_bf16(qf[kk], kf, sc[j], 0, 0, 0);
      }
    const bool boundary = (p0 + 63 > t0);
    float mnew[4], alpha[4];
#pragma unroll
    for (int rg = 0; rg < 4; ++rg) {
      const int t = (qbase + wave * 16 + l4 * 4 + rg) >> 3;
      float mx = m_row[rg];
#pragma unroll
      for (int j = 0; j < 4; ++j) {
        float vsc = sc[j][rg];
        if (boundary && (p0 + j * 16 + l15) > t) vsc = -1e30f;
        sc[j][rg] = vsc;
        mx = fmaxf(mx, vsc);
      }
      for (int mm = 1; mm < 16; mm <<= 1) mx = fmaxf(mx, __shfl_xor(mx, mm));
      mnew[rg] = mx;
    }
#pragma unroll
    for (int rg = 0; rg < 4; ++rg) {
      float sum = 0.f;
#pragma unroll
      for (int j = 0; j < 4; ++j) {
        float e = __expf(sc[j][rg] - mnew[rg]);
        sc[j][rg] = e;
        sum += e;
      }
      for (int mm = 1; mm < 16; mm <<= 1) sum += __shfl_xor(sum, mm);
      alpha[rg] = __expf(m_row[rg] - mnew[rg]);
      l_row[rg] = alpha[rg] * l_row[rg] + sum;
      m_row[rg] = mnew[rg];
    }
    // P -> LDS (bf16); rows are wave-local so no barrier needed
#pragma unroll
    for (int j = 0; j < 4; ++j)
#pragma unroll
      for (int rg = 0; rg < 4; ++rg)
        Pb[wave * 16 + l4 * 4 + rg][j * 16 + l15] = __float2bfloat16(sc[j][rg]);
#pragma unroll
    for (int jd = 0; jd < 4; ++jd)
#pragma unroll
      for (int rg = 0; rg < 4; ++rg) o_acc[jd][rg] *= alpha[rg];
    // O += P @ V   (A = P rows, B = Vt rows = output dims)
#pragma unroll
    for (int kk = 0; kk < 2; ++kk) {
      short8v pf = *(const short8v*)&Pb[wave * 16 + l15][kk * 32 + l4 * 8];
#pragma unroll
      for (int jd = 0; jd < 4; ++jd) {
        short8v vf = *(const short8v*)&Vt[jd * 16 + l15][kk * 32 + l4 * 8];
        o_acc[jd] = __builtin_amdgcn_mfma_f32_16x16x32_bf16(pf, vf, o_acc[jd], 0, 0, 0);
      }
    }
  }
#pragma unroll
  for (int rg = 0; rg < 4; ++rg) {
    float inv = 1.f / l_row[rg];
    int row = qbase + wave * 16 + l4 * 4 + rg;
#pragma unroll
    for (int jd = 0; jd < 4; ++jd)
      rat[(size_t)row * DR + h * DHR + jd * 16 + l15] =
          __float2bfloat16(o_acc[jd][rg] * inv);
  }
}

// ------------------------------------------------------------------- copy ---
__global__ __launch_bounds__(256) void copy4_kernel(const float4* __restrict__ in,
                                                    float4* __restrict__ out,
                                                    int n4) {
  int i = blockIdx.x * 256 + threadIdx.x;
  if (i < n4) out[i] = in[i];
}

// ----------------------------------------------------------------- launch ---
extern "C" void kernel_launch(void* const* d_in, const int* in_sizes, int n_in,
                              void* d_out, int out_size, void* d_ws,
                              size_t ws_size, hipStream_t stream) {
  const float* s   = (const float*)d_in[0];
  const float* r   = (const float*)d_in[1];
  const float* gv  = (const float*)d_in[2];
  const float* nsw = (const float*)d_in[3];
  const float* nrw = (const float*)d_in[4];
  const float* Wsq = (const float*)d_in[5];
  const float* Wsk = (const float*)d_in[6];
  const float* Wsv = (const float*)d_in[7];
  const float* Wso = (const float*)d_in[8];
  const float* Wrq = (const float*)d_in[9];
  const float* Wrk = (const float*)d_in[10];
  const float* Wrv = (const float*)d_in[11];
  const float* Wro = (const float*)d_in[12];

  float* outS = (float*)d_out;   // 1048576 fp32
  float* outR = outS + 1048576;  // 4194304 fp32

  // ---- workspace carve-up (~63 MB) ----
  char* wp = (char*)d_ws;
  float* qreg = (float*)wp;           wp += 1048576 * 4;  // 4 MB fp32 region (s_n32; later q bf16)
  __hip_bfloat16* k   = (__hip_bfloat16*)wp; wp += 8388608 * 2;  // 16 MB
  __hip_bfloat16* v   = (__hip_bfloat16*)wp; wp += 8388608 * 2;  // 16 MB
  __hip_bfloat16* qrb = (__hip_bfloat16*)wp; wp += 4194304 * 2;  // 8 MB
  __hip_bfloat16* krb = (__hip_bfloat16*)wp; wp += 524288 * 2;   // 1 MB
  __hip_bfloat16* vrbT = (__hip_bfloat16*)wp; wp += 524288 * 2;  // 1 MB [512][1024]
  __hip_bfloat16* s_nb = (__hip_bfloat16*)wp; wp += 1048576 * 2; // 2 MB
  __hip_bfloat16* r_nb = (__hip_bfloat16*)wp; wp += 4194304 * 2; // 8 MB
  __hip_bfloat16* WsqT = (__hip_bfloat16*)wp; wp += 1048576 * 2;
  __hip_bfloat16* WskT = (__hip_bfloat16*)wp; wp += 524288 * 2;
  __hip_bfloat16* WsvT = (__hip_bfloat16*)wp; wp += 524288 * 2;
  __hip_bfloat16* WsoT = (__hip_bfloat16*)wp; wp += 1048576 * 2;
  __hip_bfloat16* WrqT = (__hip_bfloat16*)wp; wp += 262144 * 2;
  __hip_bfloat16* WrkT = (__hip_bfloat16*)wp; wp += 524288 * 2;
  __hip_bfloat16* WrvT = (__hip_bfloat16*)wp; wp += 524288 * 2;
  __hip_bfloat16* WroT = (__hip_bfloat16*)wp; wp += 262144 * 2;

  // Overlays (lifetime-checked against launch order below):
  float* s_n32 = qreg;                     // dead before q-gemm writes q
  __hip_bfloat16* q = (__hip_bfloat16*)qreg;
  float* Wc = (float*)r_nb;                // r_nb dead after k/v/qr gemms
  float* u  = (float*)((char*)r_nb + 2097152);
  __hip_bfloat16* attn1b = s_nb;           // s_nb dead after kr/vr gemms
  __hip_bfloat16* ratb   = r_nb;           // Wc,u dead after part1; flash later

  // ---- weight transpose+cast to bf16 [N][K]; Wrq pre-scaled by 2^-3 ----
  transpose_bf16_kernel<<<dim3(32, 32), 256, 0, stream>>>(Wsq, WsqT, 1024, 1024, 1.f);
  transpose_bf16_kernel<<<dim3(32, 16), 256, 0, stream>>>(Wsk, WskT, 512, 1024, 1.f);
  transpose_bf16_kernel<<<dim3(32, 16), 256, 0, stream>>>(Wsv, WsvT, 512, 1024, 1.f);
  transpose_bf16_kernel<<<dim3(32, 32), 256, 0, stream>>>(Wso, WsoT, 1024, 1024, 1.f);
  transpose_bf16_kernel<<<dim3(16, 16), 256, 0, stream>>>(Wrq, WrqT, 512, 512, 0.125f);
  transpose_bf16_kernel<<<dim3(16, 32), 256, 0, stream>>>(Wrk, WrkT, 1024, 512, 1.f);
  transpose_bf16_kernel<<<dim3(16, 32), 256, 0, stream>>>(Wrv, WrvT, 1024, 512, 1.f);
  transpose_bf16_kernel<<<dim3(16, 16), 256, 0, stream>>>(Wro, WroT, 512, 512, 1.f);

  // ---- RMS norms ----
  rmsnorm_bf16_kernel<<<1024, 256, 0, stream>>>(s, nsw, s_nb, s_n32, DS);
  rmsnorm_bf16_kernel<<<8192, 256, 0, stream>>>(r, nrw, r_nb, nullptr, DR);

  // ---- bf16 GEMMs consuming r_nb (must precede Wc/u overlay writes) ----
  mfma_gemm_kernel<false, __hip_bfloat16><<<dim3(8, 64), 256, 0, stream>>>(r_nb, WskT, k, 8192, 1024, 512);
  mfma_gemm_kernel<false, __hip_bfloat16><<<dim3(8, 64), 256, 0, stream>>>(r_nb, WsvT, v, 8192, 1024, 512);
  mfma_gemm_kernel<false, __hip_bfloat16><<<dim3(4, 64), 256, 0, stream>>>(r_nb, WrqT, qrb, 8192, 512, 512);

  // ---- fp32 top-k score path: Wc = Wsq @ Wsk^T; u = s_n32 @ Wc ----
  gemm_f32_kernel<64, 4, true><<<dim3(8, 16), 256, 0, stream>>>(Wsq, Wsk, Wc, 1024, 512, 1024);
  gemm_f32_kernel<64, 4, false><<<dim3(8, 16), 256, 0, stream>>>(s_n32, Wc, u, 1024, 512, 1024);

  // ---- remaining bf16 GEMMs (q overwrites s_n32 — now dead) ----
  mfma_gemm_kernel<false, __hip_bfloat16><<<dim3(8, 8), 256, 0, stream>>>(s_nb, WsqT, q, 1024, 1024, 1024);
  mfma_gemm_kernel<false, __hip_bfloat16><<<dim3(4, 8), 256, 0, stream>>>(s_nb, WrkT, krb, 1024, 512, 1024);
  // Wrv GEMM writes V transposed for flash: vrbT[d][p], d in [0,512), p in [0,1024)
  mfma_gemm_kernel<false, __hip_bfloat16, true><<<dim3(4, 8), 256, 0, stream>>>(s_nb, WrvT, vrbT, 1024, 512, 1024);

  // ---- part 1 + part 3 ----
  part1_kernel<<<1024, 256, 0, stream>>>(s, gv, q, k, v, r, nrw, u, attn1b, outS);
  mfma_gemm_kernel<true, float><<<dim3(8, 8), 256, 0, stream>>>(attn1b, WsoT, outS, 1024, 1024, 1024);

  // ---- part 2 ----
  copy4_kernel<<<4096, 256, 0, stream>>>((const float4*)r, (float4*)outR, 1048576);
  flash_mfma_kernel<<<dim3(128, 8), 256, 0, stream>>>(qrb, krb, vrbT, ratb);
  mfma_gemm_kernel<true, float><<<dim3(4, 64), 256, 0, stream>>>(ratb, WroT, outR, 8192, 512, 512);
}

// Round 7
// 439.283 us; speedup vs baseline: 2.8981x; 1.1998x over previous
//
#include <hip/hip_runtime.h>
#include <hip/hip_bf16.h>
#include <math.h>
#include <type_traits>

// ---------------------------------------------------------------------------
// BridgeLayer: bf16-MFMA GEMMs (global_load_lds staging) + 2-strip MFMA flash;
// fp32 top-k score path.  B=1,T=1024,N=8,H=8,D_S=1024,D_R=512,TOPK=4
// ---------------------------------------------------------------------------

#define T_DIM 1024
#define N_SLOT 8
#define DS 1024
#define DR 512
#define NH 8
#define DHS 128
#define DHR 64

typedef __attribute__((ext_vector_type(8))) short short8v;
typedef __attribute__((ext_vector_type(4))) float floatx4;

#define GLDS(gptr, lptr)                                                     \
  __builtin_amdgcn_global_load_lds(                                          \
      (__attribute__((address_space(1))) void*)(gptr),                       \
      (__attribute__((address_space(3))) void*)(lptr), 16, 0, 0)

// ------------------------------------------------------- fused rmsnorms ----
// blocks [0,1024): s rows (width 1024, bf16+fp32 out); [1024,9216): r rows
// (width 512, bf16 out).
__global__ __launch_bounds__(256) void rmsnorm_both_kernel(
    const float* __restrict__ s, const float* __restrict__ r,
    const float* __restrict__ nsw, const float* __restrict__ nrw,
    __hip_bfloat16* __restrict__ s_nb, float* __restrict__ s_n32,
    __hip_bfloat16* __restrict__ r_nb) {
  const bool is_s = blockIdx.x < 1024;
  const int row = is_s ? blockIdx.x : blockIdx.x - 1024;
  const int width = is_s ? DS : DR;
  const float* x = is_s ? s : r;
  const float* w = is_s ? nsw : nrw;
  const int tid = threadIdx.x;
  const size_t base = (size_t)row * width;
  float ss = 0.f;
  for (int i = tid; i < width; i += 256) {
    float v = x[base + i];
    ss += v * v;
  }
  for (int m = 32; m >= 1; m >>= 1) ss += __shfl_xor(ss, m);
  __shared__ float red[4];
  const int wave = tid >> 6, lane = tid & 63;
  if (lane == 0) red[wave] = ss;
  __syncthreads();
  float total = red[0] + red[1] + red[2] + red[3];
  float scale = rsqrtf(total / (float)width + 1e-6f);
  for (int i = tid; i < width; i += 256) {
    float val = x[base + i] * scale * w[i];
    if (is_s) {
      s_nb[base + i] = __float2bfloat16(val);
      s_n32[base + i] = val;
    } else {
      r_nb[base + i] = __float2bfloat16(val);
    }
  }
}

// ------------------------------------------- fused weight transpose+cast ----
struct TJob { const float* W; __hip_bfloat16* Wt; int K; int N; float scale; int b0; };
struct TJobs { TJob j[8]; };

__global__ __launch_bounds__(256) void transpose_all_kernel(TJobs jobs) {
  int ji = 0;
#pragma unroll
  for (int t = 1; t < 8; ++t)
    if ((int)blockIdx.x >= jobs.j[t].b0) ji = t;
  const TJob J = jobs.j[ji];
  const int lb = blockIdx.x - J.b0;
  const int nbx = J.N >> 5;
  const int bx = lb % nbx, by = lb / nbx;
  const int n0 = bx * 32, k0 = by * 32;
  __shared__ float t[32][33];
  const int tx = threadIdx.x & 31, ty = threadIdx.x >> 5;
#pragma unroll
  for (int i = 0; i < 4; ++i) {
    int kk = ty + i * 8;
    t[kk][tx] = J.W[(size_t)(k0 + kk) * J.N + n0 + tx];
  }
  __syncthreads();
#pragma unroll
  for (int i = 0; i < 4; ++i) {
    int nn = ty + i * 8;
    J.Wt[(size_t)(n0 + nn) * J.K + k0 + tx] = __float2bfloat16(t[tx][nn] * J.scale);
  }
}

// --------------------------------------------------------------- fp32 gemm --
// C[M,N] = A[M,K] @ B.  BT=false: B is [K][N]; BT=true: B is [N][K] (NT).
template <int BS, int TT, bool BT>
__global__ __launch_bounds__(256) void gemm_f32_kernel(
    const float* __restrict__ A, const float* __restrict__ B,
    float* __restrict__ C, int M, int N, int K) {
  __shared__ __align__(16) float Ast[16][BS + 4];
  __shared__ __align__(16) float Bs[16][BS + 4];
  const int tid = threadIdx.x;
  const int tx = tid & 15, ty = tid >> 4;
  const int row0 = blockIdx.y * BS, col0 = blockIdx.x * BS;
  float acc[TT][TT] = {};
  constexpr int NF4 = BS * 16 / 4;
  for (int k0 = 0; k0 < K; k0 += 16) {
    __syncthreads();
    for (int l = tid; l < NF4; l += 256) {
      int lr = l >> 2, lk = (l & 3) << 2;
      float4 a4 = *(const float4*)&A[(size_t)(row0 + lr) * K + k0 + lk];
      Ast[lk + 0][lr] = a4.x;
      Ast[lk + 1][lr] = a4.y;
      Ast[lk + 2][lr] = a4.z;
      Ast[lk + 3][lr] = a4.w;
      if (BT) {
        float4 b4 = *(const float4*)&B[(size_t)(col0 + lr) * K + k0 + lk];
        Bs[lk + 0][lr] = b4.x;
        Bs[lk + 1][lr] = b4.y;
        Bs[lk + 2][lr] = b4.z;
        Bs[lk + 3][lr] = b4.w;
      } else {
        int bkk = l / (BS / 4), bc = (l % (BS / 4)) << 2;
        float4 b4 = *(const float4*)&B[(size_t)(k0 + bkk) * N + col0 + bc];
        *(float4*)&Bs[bkk][bc] = b4;
      }
    }
    __syncthreads();
#pragma unroll
    for (int kk = 0; kk < 16; ++kk) {
      float av[TT], bv[TT];
#pragma unroll
      for (int u = 0; u < TT; u += 4) {
        *(float4*)&av[u] = *(const float4*)&Ast[kk][ty * TT + u];
        *(float4*)&bv[u] = *(const float4*)&Bs[kk][tx * TT + u];
      }
#pragma unroll
      for (int i = 0; i < TT; ++i)
#pragma unroll
        for (int j = 0; j < TT; ++j) acc[i][j] += av[i] * bv[j];
    }
  }
#pragma unroll
  for (int i = 0; i < TT; ++i) {
    size_t crow = (size_t)(row0 + ty * TT + i) * N + col0;
#pragma unroll
    for (int j = 0; j < TT; j += 4) {
      *(float4*)&C[crow + tx * TT + j] =
          make_float4(acc[i][j], acc[i][j + 1], acc[i][j + 2], acc[i][j + 3]);
    }
  }
}

// -------------------------------------------------------------- MFMA gemm ---
// C (+)= A[M,K] @ Bt[N,K]^T.  MT = 128 or 64 block tile; BK=32.
// Staging via global_load_lds width=16 into unpadded LDS; the global fetch is
// XOR-swizzled (chunk ^= (row>>1)&3) so fragment ds_read_b128s spread across
// all 8 bank-groups (2-way aliasing only = free).
// TRANS: write C transposed CT[n][m] (bf16). RADD: C = R + acc (fp32).
template <int MT, bool ACCUM, typename OutT, bool TRANS = false, bool RADD = false>
__global__ __launch_bounds__(256) void mfma_gemm_kernel(
    const __hip_bfloat16* __restrict__ A, const __hip_bfloat16* __restrict__ Bt,
    OutT* __restrict__ C, const float* __restrict__ R, int M, int N, int K) {
  constexpr int FR = MT / 32;   // MFMA frags per wave dim
  constexpr int HALF = MT / 2;  // wave tile edge
  constexpr int SEG_PER_WAVE = MT / 16 / 4;
  __shared__ __hip_bfloat16 As[MT][32];
  __shared__ __hip_bfloat16 Bs[MT][32];
  const int tid = threadIdx.x;
  const int lane = tid & 63, wave = tid >> 6;
  const int wm = wave >> 1, wn = wave & 1;
  const int l15 = lane & 15, l4 = lane >> 4;
  const int row0 = blockIdx.y * MT, col0 = blockIdx.x * MT;
  const int dma_r = lane >> 2;                        // row within 16-row seg
  const int dma_c = (lane & 3) ^ ((lane >> 3) & 3);   // swizzled 8-elem chunk
  const int rd_sw = (l15 >> 1) & 3;                   // read-side swizzle
  floatx4 acc[FR][FR] = {};
  for (int k0 = 0; k0 < K; k0 += 32) {
    __syncthreads();
#pragma unroll
    for (int i = 0; i < SEG_PER_WAVE; ++i) {
      int seg = wave * SEG_PER_WAVE + i;
      GLDS(&A[(size_t)(row0 + seg * 16 + dma_r) * K + k0 + dma_c * 8],
           &As[seg * 16][0]);
      GLDS(&Bt[(size_t)(col0 + seg * 16 + dma_r) * K + k0 + dma_c * 8],
           &Bs[seg * 16][0]);
    }
    __syncthreads();
    short8v af[FR], bf[FR];
#pragma unroll
    for (int i = 0; i < FR; ++i)
      af[i] = *(const short8v*)&As[wm * HALF + i * 16 + l15][(l4 ^ rd_sw) * 8];
#pragma unroll
    for (int j = 0; j < FR; ++j)
      bf[j] = *(const short8v*)&Bs[wn * HALF + j * 16 + l15][(l4 ^ rd_sw) * 8];
#pragma unroll
    for (int i = 0; i < FR; ++i)
#pragma unroll
      for (int j = 0; j < FR; ++j)
        acc[i][j] = __builtin_amdgcn_mfma_f32_16x16x32_bf16(af[i], bf[j],
                                                            acc[i][j], 0, 0, 0);
  }
  // C/D layout: col = lane&15, row = (lane>>4)*4 + reg  [m89-verified]
#pragma unroll
  for (int i = 0; i < FR; ++i) {
    int rb = row0 + wm * HALF + i * 16 + l4 * 4;
#pragma unroll
    for (int j = 0; j < FR; ++j) {
      int cb = col0 + wn * HALF + j * 16 + l15;
      if constexpr (TRANS) {
        __hip_bfloat16 pk[4];
#pragma unroll
        for (int rg = 0; rg < 4; ++rg) pk[rg] = __float2bfloat16(acc[i][j][rg]);
        *(ushort4*)&C[(size_t)cb * M + rb] = *(const ushort4*)pk;
      } else {
#pragma unroll
        for (int rg = 0; rg < 4; ++rg) {
          size_t idx = (size_t)(rb + rg) * N + cb;
          if constexpr (std::is_same<OutT, __hip_bfloat16>::value) {
            C[idx] = __float2bfloat16(acc[i][j][rg]);
          } else if constexpr (RADD) {
            C[idx] = R[idx] + acc[i][j][rg];
          } else if constexpr (ACCUM) {
            C[idx] += acc[i][j][rg];
          } else {
            C[idx] = acc[i][j][rg];
          }
        }
      }
    }
  }
}

// ---------------------------------------------- part1 + part3 (per t row) ---
__global__ __launch_bounds__(256) void part1_kernel(
    const float* __restrict__ s, const float* __restrict__ gv,
    const __hip_bfloat16* __restrict__ q, const __hip_bfloat16* __restrict__ k,
    const __hip_bfloat16* __restrict__ v, const float* __restrict__ r,
    const float* __restrict__ nrw, const float* __restrict__ u,
    __hip_bfloat16* __restrict__ attn1, float* __restrict__ outS) {
  __shared__ float qs[DS];
  __shared__ float dots[NH][N_SLOT];
  __shared__ float wattn[NH][N_SLOT];
  __shared__ float w8[N_SLOT];
  __shared__ float spv[N_SLOT];
  __shared__ float gateL;
  const int t = blockIdx.x;
  const int tid = threadIdx.x;
  for (int i = tid; i < DS; i += 256) qs[i] = __bfloat162float(q[(size_t)t * DS + i]);
  __syncthreads();
  const int wave = tid >> 6, lane = tid & 63;
#pragma unroll
  for (int e = 0; e < 16; ++e) {
    int pair = wave * 16 + e;
    int h = pair >> 3, n = pair & 7;
    const __hip_bfloat16* krow = &k[((size_t)t * N_SLOT + n) * DS + h * DHS];
    float a = qs[h * DHS + lane] * __bfloat162float(krow[lane]) +
              qs[h * DHS + 64 + lane] * __bfloat162float(krow[64 + lane]);
    for (int m = 32; m >= 1; m >>= 1) a += __shfl_xor(a, m);
    if (lane == 0) dots[h][n] = a;
  }
  const float scale_s = 0.08838834764831845f;  // 128^-0.5
#pragma unroll
  for (int e = 0; e < 2; ++e) {
    const int n = wave * 2 + e;
    const float* rr = &r[((size_t)t * N_SLOT + n) * DR];
    const float* ub = &u[(size_t)t * DR];
    float ssum = 0.f, dot = 0.f;
#pragma unroll
    for (int jj = 0; jj < 8; ++jj) {
      int j = lane + 64 * jj;
      float rv = rr[j];
      ssum += rv * rv;
      dot += rv * nrw[j] * ub[j];
    }
    for (int m = 32; m >= 1; m >>= 1) {
      ssum += __shfl_xor(ssum, m);
      dot += __shfl_xor(dot, m);
    }
    if (lane == 0) {
      float rs = rsqrtf(ssum / (float)DR + 1e-6f);
      spv[n] = scale_s * rs * dot;
    }
  }
  __syncthreads();
  if (tid < 8) {
    int h = tid;
    float vmax = -1e30f;
    for (int n = 0; n < 8; ++n) vmax = fmaxf(vmax, dots[h][n] * scale_s);
    float sum = 0.f;
    for (int n = 0; n < 8; ++n) {
      float e = __expf(dots[h][n] * scale_s - vmax);
      wattn[h][n] = e;
      sum += e;
    }
    float inv = 1.f / sum;
    for (int n = 0; n < 8; ++n) wattn[h][n] *= inv;
  }
  if (tid == 64) {
    float sv[8];
    for (int n = 0; n < 8; ++n) sv[n] = spv[n];
    bool used[8] = {};
    float vals[4];
    int idxs[4];
    for (int kk = 0; kk < 4; ++kk) {
      float best = -1e30f;
      int bi = 0;
      for (int n = 0; n < 8; ++n)
        if (!used[n] && sv[n] > best) { best = sv[n]; bi = n; }
      used[bi] = true;
      vals[kk] = best;
      idxs[kk] = bi;
    }
    float mx = vals[0];
    float wv[4];
    float sum = 0.f;
    for (int kk = 0; kk < 4; ++kk) {
      wv[kk] = __expf(vals[kk] - mx);
      sum += wv[kk];
    }
    float inv = 1.f / sum;
    for (int n = 0; n < 8; ++n) w8[n] = 0.f;
    for (int kk = 0; kk < 4; ++kk) w8[idxs[kk]] = wv[kk] * inv;
    gateL = gv[t];
  }
  __syncthreads();
  const float gate = gateL;
#pragma unroll
  for (int jj = 0; jj < 4; ++jj) {
    int d = tid + 256 * jj;
    int hh = d >> 7;
    float a1 = 0.f, a2 = 0.f;
#pragma unroll
    for (int n = 0; n < 8; ++n) {
      float vv = __bfloat162float(v[((size_t)t * N_SLOT + n) * DS + d]);
      a1 += wattn[hh][n] * vv;
      a2 += w8[n] * vv;
    }
    attn1[(size_t)t * DS + d] = __float2bfloat16(a1);
    outS[(size_t)t * DS + d] = s[(size_t)t * DS + d] + gate * a2;
  }
}

// ------------------------------------------- part2 MFMA flash attention -----
// Q-tile 128 rows; each wave owns TWO 16-row strips (wave*16 and 64+wave*16)
// sharing the staged K/V tile -> 2x MFMA/VALU work per barrier, 2 independent
// dependency chains per wave. Online softmax register-resident per strip.
__global__ __launch_bounds__(256) void flash_mfma_kernel(
    const __hip_bfloat16* __restrict__ qb, const __hip_bfloat16* __restrict__ kb,
    const __hip_bfloat16* __restrict__ vbT, __hip_bfloat16* __restrict__ rat) {
  __shared__ __align__(16) __hip_bfloat16 Qs[128][72];
  __shared__ __align__(16) __hip_bfloat16 Ks[64][72];
  __shared__ __align__(16) __hip_bfloat16 Vt[64][72];   // [dim][key]
  __shared__ __align__(16) __hip_bfloat16 Pb[128][72];  // [qrow][key] wave-local
  const int tid = threadIdx.x;
  const int lane = tid & 63, wave = tid >> 6;
  const int l15 = lane & 15, l4 = lane >> 4;
  const int h = blockIdx.y;
  const int qbase = blockIdx.x * 128;

  for (int g = tid; g < 1024; g += 256) {
    int rr = g >> 3, c = (g & 7) * 8;
    *(ulonglong2*)&Qs[rr][c] =
        *(const ulonglong2*)&qb[(size_t)(qbase + rr) * DR + h * DHR + c];
  }
  __syncthreads();
  const int sA = wave * 16;        // strip A row base (in tile)
  const int sB = 64 + wave * 16;   // strip B row base
  short8v qfA[2], qfB[2];
#pragma unroll
  for (int kk = 0; kk < 2; ++kk) {
    qfA[kk] = *(const short8v*)&Qs[sA + l15][kk * 32 + l4 * 8];
    qfB[kk] = *(const short8v*)&Qs[sB + l15][kk * 32 + l4 * 8];
  }
  const int tAmin = (qbase + sA) >> 3, tAmax = (qbase + sA + 15) >> 3;
  const int tBmin = (qbase + sB) >> 3, tBmax = (qbase + sB + 15) >> 3;

  float mA[4], lA[4], mB[4], lB[4];
#pragma unroll
  for (int rg = 0; rg < 4; ++rg) {
    mA[rg] = -1e30f; lA[rg] = 0.f;
    mB[rg] = -1e30f; lB[rg] = 0.f;
  }
  floatx4 oA[4] = {}, oB[4] = {};

  const int ntiles = (((qbase + 127) >> 3) >> 6) + 1;
  for (int pt = 0; pt < ntiles; ++pt) {
    const int p0 = pt << 6;
    __syncthreads();
    for (int g = tid; g < 512; g += 256) {
      int rr = g >> 3, c = (g & 7) * 8;
      *(ulonglong2*)&Ks[rr][c] =
          *(const ulonglong2*)&kb[(size_t)(p0 + rr) * DR + h * DHR + c];
      *(ulonglong2*)&Vt[rr][c] =
          *(const ulonglong2*)&vbT[(size_t)(h * DHR + rr) * T_DIM + p0 + c];
    }
    __syncthreads();
    const bool actA = (p0 <= tAmax);       // wave-uniform
    const bool actB = (p0 <= tBmax);
    if (actA) {
      floatx4 sc[4] = {};
#pragma unroll
      for (int j = 0; j < 4; ++j)
#pragma unroll
        for (int kk = 0; kk < 2; ++kk) {
          short8v kf = *(const short8v*)&Ks[j * 16 + l15][kk * 32 + l4 * 8];
          sc[j] = __builtin_amdgcn_mfma_f32_16x16x32_bf16(qfA[kk], kf, sc[j], 0, 0, 0);
        }
      const bool bnd = (p0 + 63 > tAmin);
      float mnew[4], alpha[4];
#pragma unroll
      for (int rg = 0; rg < 4; ++rg) {
        const int t = (qbase + sA + l4 * 4 + rg) >> 3;
        float mx = mA[rg];
#pragma unroll
        for (int j = 0; j < 4; ++j) {
          float vsc = sc[j][rg];
          if (bnd && (p0 + j * 16 + l15) > t) vsc = -1e30f;
          sc[j][rg] = vsc;
          mx = fmaxf(mx, vsc);
        }
        for (int mm = 1; mm < 16; mm <<= 1) mx = fmaxf(mx, __shfl_xor(mx, mm));
        mnew[rg] = mx;
      }
#pragma unroll
      for (int rg = 0; rg < 4; ++rg) {
        float sum = 0.f;
#pragma unroll
        for (int j = 0; j < 4; ++j) {
          float e = __expf(sc[j][rg] - mnew[rg]);
          sc[j][rg] = e;
          sum += e;
        }
        for (int mm = 1; mm < 16; mm <<= 1) sum += __shfl_xor(sum, mm);
        alpha[rg] = __expf(mA[rg] - mnew[rg]);
        lA[rg] = alpha[rg] * lA[rg] + sum;
        mA[rg] = mnew[rg];
      }
#pragma unroll
      for (int j = 0; j < 4; ++j)
#pragma unroll
        for (int rg = 0; rg < 4; ++rg)
          Pb[sA + l4 * 4 + rg][j * 16 + l15] = __float2bfloat16(sc[j][rg]);
#pragma unroll
      for (int jd = 0; jd < 4; ++jd)
#pragma unroll
        for (int rg = 0; rg < 4; ++rg) oA[jd][rg] *= alpha[rg];
    }
    if (actB) {
      floatx4 sc[4] = {};
#pragma unroll
      for (int j = 0; j < 4; ++j)
#pragma unroll
        for (int kk = 0; kk < 2; ++kk) {
          short8v kf = *(const short8v*)&Ks[j * 16 + l15][kk * 32 + l4 * 8];
          sc[j] = __builtin_amdgcn_mfma_f32_16x16x32_bf16(qfB[kk], kf, sc[j], 0, 0, 0);
        }
      const bool bnd = (p0 + 63 > tBmin);
      float mnew[4], alpha[4];
#pragma unroll
      for (int rg = 0; rg < 4; ++rg) {
        const int t = (qbase + sB + l4 * 4 + rg) >> 3;
        float mx = mB[rg];
#pragma unroll
        for (int j = 0; j < 4; ++j) {
          float vsc = sc[j][rg];
          if (bnd && (p0 + j * 16 + l15) > t) vsc = -1e30f;
          sc[j][rg] = vsc;
          mx = fmaxf(mx, vsc);
        }
        for (int mm = 1; mm < 16; mm <<= 1) mx = fmaxf(mx, __shfl_xor(mx, mm));
        mnew[rg] = mx;
      }
#pragma unroll
      for (int rg = 0; rg < 4; ++rg) {
        float sum = 0.f;
#pragma unroll
        for (int j = 0; j < 4; ++j) {
          float e = __expf(sc[j][rg] - mnew[rg]);
          sc[j][rg] = e;
          sum += e;
        }
        for (int mm = 1; mm < 16; mm <<= 1) sum += __shfl_xor(sum, mm);
        alpha[rg] = __expf(mB[rg] - mnew[rg]);
        lB[rg] = alpha[rg] * lB[rg] + sum;
        mB[rg] = mnew[rg];
      }
#pragma unroll
      for (int j = 0; j < 4; ++j)
#pragma unroll
        for (int rg = 0; rg < 4; ++rg)
          Pb[sB + l4 * 4 + rg][j * 16 + l15] = __float2bfloat16(sc[j][rg]);
#pragma unroll
      for (int jd = 0; jd < 4; ++jd)
#pragma unroll
        for (int rg = 0; rg < 4; ++rg) oB[jd][rg] *= alpha[rg];
    }
    // PV for both strips (Pb rows wave-local; lgkm dependency handled by compiler)
#pragma unroll
    for (int kk = 0; kk < 2; ++kk) {
      if (actA) {
        short8v pf = *(const short8v*)&Pb[sA + l15][kk * 32 + l4 * 8];
#pragma unroll
        for (int jd = 0; jd < 4; ++jd) {
          short8v vf = *(const short8v*)&Vt[jd * 16 + l15][kk * 32 + l4 * 8];
          oA[jd] = __builtin_amdgcn_mfma_f32_16x16x32_bf16(pf, vf, oA[jd], 0, 0, 0);
        }
      }
      if (actB) {
        short8v pf = *(const short8v*)&Pb[sB + l15][kk * 32 + l4 * 8];
#pragma unroll
        for (int jd = 0; jd < 4; ++jd) {
          short8v vf = *(const short8v*)&Vt[jd * 16 + l15][kk * 32 + l4 * 8];
          oB[jd] = __builtin_amdgcn_mfma_f32_16x16x32_bf16(pf, vf, oB[jd], 0, 0, 0);
        }
      }
    }
  }
#pragma unroll
  for (int rg = 0; rg < 4; ++rg) {
    float invA = 1.f / lA[rg];
    float invB = 1.f / lB[rg];
    int rowA = qbase + sA + l4 * 4 + rg;
    int rowB = qbase + sB + l4 * 4 + rg;
#pragma unroll
    for (int jd = 0; jd < 4; ++jd) {
      rat[(size_t)rowA * DR + h * DHR + jd * 16 + l15] =
          __float2bfloat16(oA[jd][rg] * invA);
      rat[(size_t)rowB * DR + h * DHR + jd * 16 + l15] =
          __float2bfloat16(oB[jd][rg] * invB);
    }
  }
}

// ----------------------------------------------------------------- launch ---
extern "C" void kernel_launch(void* const* d_in, const int* in_sizes, int n_in,
                              void* d_out, int out_size, void* d_ws,
                              size_t ws_size, hipStream_t stream) {
  const float* s   = (const float*)d_in[0];
  const float* r   = (const float*)d_in[1];
  const float* gv  = (const float*)d_in[2];
  const float* nsw = (const float*)d_in[3];
  const float* nrw = (const float*)d_in[4];
  const float* Wsq = (const float*)d_in[5];
  const float* Wsk = (const float*)d_in[6];
  const float* Wsv = (const float*)d_in[7];
  const float* Wso = (const float*)d_in[8];
  const float* Wrq = (const float*)d_in[9];
  const float* Wrk = (const float*)d_in[10];
  const float* Wrv = (const float*)d_in[11];
  const float* Wro = (const float*)d_in[12];

  float* outS = (float*)d_out;   // 1048576 fp32
  float* outR = outS + 1048576;  // 4194304 fp32

  // ---- workspace carve-up ----
  char* wp = (char*)d_ws;
  float* qreg = (float*)wp;           wp += 1048576 * 4;  // s_n32, later q bf16
  __hip_bfloat16* k   = (__hip_bfloat16*)wp; wp += 8388608 * 2;
  __hip_bfloat16* v   = (__hip_bfloat16*)wp; wp += 8388608 * 2;
  __hip_bfloat16* qrb = (__hip_bfloat16*)wp; wp += 4194304 * 2;
  __hip_bfloat16* krb = (__hip_bfloat16*)wp; wp += 524288 * 2;
  __hip_bfloat16* vrbT = (__hip_bfloat16*)wp; wp += 524288 * 2;  // [512][1024]
  __hip_bfloat16* s_nb = (__hip_bfloat16*)wp; wp += 1048576 * 2;
  __hip_bfloat16* r_nb = (__hip_bfloat16*)wp; wp += 4194304 * 2;
  __hip_bfloat16* WsqT = (__hip_bfloat16*)wp; wp += 1048576 * 2;
  __hip_bfloat16* WskT = (__hip_bfloat16*)wp; wp += 524288 * 2;
  __hip_bfloat16* WsvT = (__hip_bfloat16*)wp; wp += 524288 * 2;
  __hip_bfloat16* WsoT = (__hip_bfloat16*)wp; wp += 1048576 * 2;
  __hip_bfloat16* WrqT = (__hip_bfloat16*)wp; wp += 262144 * 2;
  __hip_bfloat16* WrkT = (__hip_bfloat16*)wp; wp += 524288 * 2;
  __hip_bfloat16* WrvT = (__hip_bfloat16*)wp; wp += 524288 * 2;
  __hip_bfloat16* WroT = (__hip_bfloat16*)wp; wp += 262144 * 2;

  // Overlays (lifetimes checked against launch order):
  float* s_n32 = qreg;
  __hip_bfloat16* q = (__hip_bfloat16*)qreg;
  float* Wc = (float*)r_nb;
  float* u  = (float*)((char*)r_nb + 2097152);
  __hip_bfloat16* attn1b = s_nb;
  __hip_bfloat16* ratb   = r_nb;

  // ---- fused weight transpose+cast (Wrq pre-scaled by 2^-3) ----
  TJobs jobs = {{
      {Wsq, WsqT, 1024, 1024, 1.f, 0},
      {Wsk, WskT, 512, 1024, 1.f, 1024},
      {Wsv, WsvT, 512, 1024, 1.f, 1536},
      {Wso, WsoT, 1024, 1024, 1.f, 2048},
      {Wrq, WrqT, 512, 512, 0.125f, 3072},
      {Wrk, WrkT, 1024, 512, 1.f, 3328},
      {Wrv, WrvT, 1024, 512, 1.f, 3840},
      {Wro, WroT, 512, 512, 1.f, 4352},
  }};
  transpose_all_kernel<<<4608, 256, 0, stream>>>(jobs);

  // ---- fused RMS norms ----
  rmsnorm_both_kernel<<<9216, 256, 0, stream>>>(s, r, nsw, nrw, s_nb, s_n32, r_nb);

  // ---- bf16 GEMMs consuming r_nb (precede Wc/u overlay writes) ----
  mfma_gemm_kernel<128, false, __hip_bfloat16><<<dim3(8, 64), 256, 0, stream>>>(r_nb, WskT, k, nullptr, 8192, 1024, 512);
  mfma_gemm_kernel<128, false, __hip_bfloat16><<<dim3(8, 64), 256, 0, stream>>>(r_nb, WsvT, v, nullptr, 8192, 1024, 512);
  mfma_gemm_kernel<128, false, __hip_bfloat16><<<dim3(4, 64), 256, 0, stream>>>(r_nb, WrqT, qrb, nullptr, 8192, 512, 512);

  // ---- fp32 top-k score path: Wc = Wsq @ Wsk^T; u = s_n32 @ Wc ----
  gemm_f32_kernel<64, 4, true><<<dim3(8, 16), 256, 0, stream>>>(Wsq, Wsk, Wc, 1024, 512, 1024);
  gemm_f32_kernel<64, 4, false><<<dim3(8, 16), 256, 0, stream>>>(s_n32, Wc, u, 1024, 512, 1024);

  // ---- remaining bf16 GEMMs, 64-tile (q overwrites s_n32 — now dead) ----
  mfma_gemm_kernel<64, false, __hip_bfloat16><<<dim3(16, 16), 256, 0, stream>>>(s_nb, WsqT, q, nullptr, 1024, 1024, 1024);
  mfma_gemm_kernel<64, false, __hip_bfloat16><<<dim3(8, 16), 256, 0, stream>>>(s_nb, WrkT, krb, nullptr, 1024, 512, 1024);
  mfma_gemm_kernel<64, false, __hip_bfloat16, true><<<dim3(8, 16), 256, 0, stream>>>(s_nb, WrvT, vrbT, nullptr, 1024, 512, 1024);

  // ---- part 1 + part 3 ----
  part1_kernel<<<1024, 256, 0, stream>>>(s, gv, q, k, v, r, nrw, u, attn1b, outS);
  mfma_gemm_kernel<64, true, float><<<dim3(16, 16), 256, 0, stream>>>(attn1b, WsoT, outS, nullptr, 1024, 1024, 1024);

  // ---- part 2: flash + (outR = r + rat @ Wro) fused epilogue ----
  flash_mfma_kernel<<<dim3(64, 8), 256, 0, stream>>>(qrb, krb, vrbT, ratb);
  mfma_gemm_kernel<128, false, float, false, true><<<dim3(4, 64), 256, 0, stream>>>(ratb, WroT, outR, r, 8192, 512, 512);
}

// Round 8
// 321.748 us; speedup vs baseline: 3.9568x; 1.3653x over previous
//
#include <hip/hip_runtime.h>
#include <hip/hip_bf16.h>
#include <math.h>
#include <type_traits>

// ---------------------------------------------------------------------------
// BridgeLayer: batched bf16-MFMA GEMMs (global_load_lds) + S^T MFMA flash
// (in-register softmax); fp32 split-K top-k score path.
// B=1,T=1024,N=8,H=8,D_S=1024,D_R=512,TOPK=4
// ---------------------------------------------------------------------------

#define T_DIM 1024
#define N_SLOT 8
#define DS 1024
#define DR 512
#define NH 8
#define DHS 128
#define DHR 64

typedef __attribute__((ext_vector_type(8))) short short8v;
typedef __attribute__((ext_vector_type(4))) float floatx4;

#define GLDS(gptr, lptr)                                                     \
  __builtin_amdgcn_global_load_lds(                                          \
      (__attribute__((address_space(1))) void*)(gptr),                       \
      (__attribute__((address_space(3))) void*)(lptr), 16, 0, 0)

// ---------------------------------------- prep: transposes + rmsnorms -------
struct TJob { const float* W; __hip_bfloat16* Wt; int K; int N; float scale; int b0; };
struct TJobs { TJob j[8]; };

// blocks [0,4608): weight transpose+cast; [4608,13824): rmsnorms (s then r).
__global__ __launch_bounds__(256) void prep_kernel(
    TJobs jobs, const float* __restrict__ s, const float* __restrict__ r,
    const float* __restrict__ nsw, const float* __restrict__ nrw,
    __hip_bfloat16* __restrict__ s_nb, float* __restrict__ s_n32,
    __hip_bfloat16* __restrict__ r_nb) {
  __shared__ float sh[32][33];
  const int tid = threadIdx.x;
  if (blockIdx.x < 4608) {
    int ji = 0;
#pragma unroll
    for (int t = 1; t < 8; ++t)
      if ((int)blockIdx.x >= jobs.j[t].b0) ji = t;
    const TJob J = jobs.j[ji];
    const int lb = blockIdx.x - J.b0;
    const int nbx = J.N >> 5;
    const int n0 = (lb % nbx) * 32, k0 = (lb / nbx) * 32;
    const int tx = tid & 31, ty = tid >> 5;
#pragma unroll
    for (int i = 0; i < 4; ++i) {
      int kk = ty + i * 8;
      sh[kk][tx] = J.W[(size_t)(k0 + kk) * J.N + n0 + tx];
    }
    __syncthreads();
#pragma unroll
    for (int i = 0; i < 4; ++i) {
      int nn = ty + i * 8;
      J.Wt[(size_t)(n0 + nn) * J.K + k0 + tx] = __float2bfloat16(sh[tx][nn] * J.scale);
    }
  } else {
    const int blk = blockIdx.x - 4608;
    const bool is_s = blk < 1024;
    const int row = is_s ? blk : blk - 1024;
    const int width = is_s ? DS : DR;
    const float* x = is_s ? s : r;
    const float* w = is_s ? nsw : nrw;
    const size_t base = (size_t)row * width;
    float ss = 0.f;
    for (int i = tid; i < width; i += 256) {
      float v = x[base + i];
      ss += v * v;
    }
    for (int m = 32; m >= 1; m >>= 1) ss += __shfl_xor(ss, m);
    const int wave = tid >> 6, lane = tid & 63;
    if (lane == 0) sh[0][wave] = ss;
    __syncthreads();
    float total = sh[0][0] + sh[0][1] + sh[0][2] + sh[0][3];
    float scale = rsqrtf(total / (float)width + 1e-6f);
    for (int i = tid; i < width; i += 256) {
      float val = x[base + i] * scale * w[i];
      if (is_s) {
        s_nb[base + i] = __float2bfloat16(val);
        s_n32[base + i] = val;
      } else {
        r_nb[base + i] = __float2bfloat16(val);
      }
    }
  }
}

// ------------------------------------------------ fp32 gemm (split-K, z=2) --
// Cz[M,N] = A[M,K/2-slice] @ B-slice; partials at C + z*M*N.
// BT: B is [N][K].  BSUM: B := B[idx] + B[idx + K*N] (summed partials).
template <int BS, int TT, bool BT, bool BSUM>
__global__ __launch_bounds__(256) void gemm_f32_kernel(
    const float* __restrict__ A, const float* __restrict__ B,
    float* __restrict__ C, int M, int N, int K) {
  __shared__ __align__(16) float Ast[16][BS + 4];
  __shared__ __align__(16) float Bs[16][BS + 4];
  const int tid = threadIdx.x;
  const int tx = tid & 15, ty = tid >> 4;
  const int row0 = blockIdx.y * BS, col0 = blockIdx.x * BS;
  const int kz = blockIdx.z;
  const int kbeg = kz * (K >> 1), kend = kbeg + (K >> 1);
  float* Cz = C + (size_t)kz * M * N;
  const size_t bsz = (size_t)K * N;
  float acc[TT][TT] = {};
  constexpr int NF4 = BS * 16 / 4;
  for (int k0 = kbeg; k0 < kend; k0 += 16) {
    __syncthreads();
    for (int l = tid; l < NF4; l += 256) {
      int lr = l >> 2, lk = (l & 3) << 2;
      float4 a4 = *(const float4*)&A[(size_t)(row0 + lr) * K + k0 + lk];
      Ast[lk + 0][lr] = a4.x;
      Ast[lk + 1][lr] = a4.y;
      Ast[lk + 2][lr] = a4.z;
      Ast[lk + 3][lr] = a4.w;
      if (BT) {
        float4 b4 = *(const float4*)&B[(size_t)(col0 + lr) * K + k0 + lk];
        Bs[lk + 0][lr] = b4.x;
        Bs[lk + 1][lr] = b4.y;
        Bs[lk + 2][lr] = b4.z;
        Bs[lk + 3][lr] = b4.w;
      } else {
        int bkk = l / (BS / 4), bc = (l % (BS / 4)) << 2;
        size_t bidx = (size_t)(k0 + bkk) * N + col0 + bc;
        float4 b4 = *(const float4*)&B[bidx];
        if (BSUM) {
          float4 b2 = *(const float4*)&B[bsz + bidx];
          b4.x += b2.x; b4.y += b2.y; b4.z += b2.z; b4.w += b2.w;
        }
        *(float4*)&Bs[bkk][bc] = b4;
      }
    }
    __syncthreads();
#pragma unroll
    for (int kk = 0; kk < 16; ++kk) {
      float av[TT], bv[TT];
#pragma unroll
      for (int u = 0; u < TT; u += 4) {
        *(float4*)&av[u] = *(const float4*)&Ast[kk][ty * TT + u];
        *(float4*)&bv[u] = *(const float4*)&Bs[kk][tx * TT + u];
      }
#pragma unroll
      for (int i = 0; i < TT; ++i)
#pragma unroll
        for (int j = 0; j < TT; ++j) acc[i][j] += av[i] * bv[j];
    }
  }
#pragma unroll
  for (int i = 0; i < TT; ++i) {
    size_t crow = (size_t)(row0 + ty * TT + i) * N + col0;
#pragma unroll
    for (int j = 0; j < TT; j += 4) {
      *(float4*)&Cz[crow + tx * TT + j] =
          make_float4(acc[i][j], acc[i][j + 1], acc[i][j + 2], acc[i][j + 3]);
    }
  }
}

// -------------------------------------------------------------- MFMA gemm ---
// Single-job version (Wso/Wro epilogues). C (+)= A[M,K] @ Bt[N,K]^T.
// RADD: C = R + acc.
template <int MT, bool ACCUM, typename OutT, bool RADD = false>
__global__ __launch_bounds__(256) void mfma_gemm_kernel(
    const __hip_bfloat16* __restrict__ A, const __hip_bfloat16* __restrict__ Bt,
    OutT* __restrict__ C, const float* __restrict__ R, int M, int N, int K) {
  constexpr int FR = MT / 32;
  constexpr int HALF = MT / 2;
  constexpr int SEG_PER_WAVE = MT / 16 / 4;
  __shared__ __hip_bfloat16 As[MT][32];
  __shared__ __hip_bfloat16 Bs[MT][32];
  const int tid = threadIdx.x;
  const int lane = tid & 63, wave = tid >> 6;
  const int wm = wave >> 1, wn = wave & 1;
  const int l15 = lane & 15, l4 = lane >> 4;
  const int row0 = blockIdx.y * MT, col0 = blockIdx.x * MT;
  const int dma_r = lane >> 2;
  const int dma_c = (lane & 3) ^ ((lane >> 3) & 3);
  const int rd_sw = (l15 >> 1) & 3;
  floatx4 acc[FR][FR] = {};
  for (int k0 = 0; k0 < K; k0 += 32) {
    __syncthreads();
#pragma unroll
    for (int i = 0; i < SEG_PER_WAVE; ++i) {
      int seg = wave * SEG_PER_WAVE + i;
      GLDS(&A[(size_t)(row0 + seg * 16 + dma_r) * K + k0 + dma_c * 8], &As[seg * 16][0]);
      GLDS(&Bt[(size_t)(col0 + seg * 16 + dma_r) * K + k0 + dma_c * 8], &Bs[seg * 16][0]);
    }
    __syncthreads();
    short8v af[FR], bf[FR];
#pragma unroll
    for (int i = 0; i < FR; ++i)
      af[i] = *(const short8v*)&As[wm * HALF + i * 16 + l15][(l4 ^ rd_sw) * 8];
#pragma unroll
    for (int j = 0; j < FR; ++j)
      bf[j] = *(const short8v*)&Bs[wn * HALF + j * 16 + l15][(l4 ^ rd_sw) * 8];
#pragma unroll
    for (int i = 0; i < FR; ++i)
#pragma unroll
      for (int j = 0; j < FR; ++j)
        acc[i][j] = __builtin_amdgcn_mfma_f32_16x16x32_bf16(af[i], bf[j], acc[i][j], 0, 0, 0);
  }
#pragma unroll
  for (int i = 0; i < FR; ++i) {
    int rb = row0 + wm * HALF + i * 16 + l4 * 4;
#pragma unroll
    for (int j = 0; j < FR; ++j) {
      int cb = col0 + wn * HALF + j * 16 + l15;
#pragma unroll
      for (int rg = 0; rg < 4; ++rg) {
        size_t idx = (size_t)(rb + rg) * N + cb;
        if constexpr (std::is_same<OutT, __hip_bfloat16>::value) {
          C[idx] = __float2bfloat16(acc[i][j][rg]);
        } else if constexpr (RADD) {
          C[idx] = R[idx] + acc[i][j][rg];
        } else if constexpr (ACCUM) {
          C[idx] += acc[i][j][rg];
        } else {
          C[idx] = acc[i][j][rg];
        }
      }
    }
  }
}

// Batched version: shared A, per-job Bt/C/N, bf16 out, runtime trans flag.
struct GJob { const __hip_bfloat16* Bt; __hip_bfloat16* C; int N; int b0; int trans; };
struct GJobs { GJob j[3]; };

template <int MT>
__global__ __launch_bounds__(256) void mfma_gemm_batch_kernel(
    const __hip_bfloat16* __restrict__ A, GJobs jobs, int M, int K) {
  constexpr int FR = MT / 32;
  constexpr int HALF = MT / 2;
  constexpr int SEG_PER_WAVE = MT / 16 / 4;
  __shared__ __hip_bfloat16 As[MT][32];
  __shared__ __hip_bfloat16 Bs[MT][32];
  int ji = 0;
#pragma unroll
  for (int t = 1; t < 3; ++t)
    if ((int)blockIdx.x >= jobs.j[t].b0) ji = t;
  const GJob J = jobs.j[ji];
  const int lb = blockIdx.x - J.b0;
  const int nbx = J.N / MT;
  const int row0 = (lb / nbx) * MT, col0 = (lb % nbx) * MT;
  const int tid = threadIdx.x;
  const int lane = tid & 63, wave = tid >> 6;
  const int wm = wave >> 1, wn = wave & 1;
  const int l15 = lane & 15, l4 = lane >> 4;
  const int dma_r = lane >> 2;
  const int dma_c = (lane & 3) ^ ((lane >> 3) & 3);
  const int rd_sw = (l15 >> 1) & 3;
  floatx4 acc[FR][FR] = {};
  for (int k0 = 0; k0 < K; k0 += 32) {
    __syncthreads();
#pragma unroll
    for (int i = 0; i < SEG_PER_WAVE; ++i) {
      int seg = wave * SEG_PER_WAVE + i;
      GLDS(&A[(size_t)(row0 + seg * 16 + dma_r) * K + k0 + dma_c * 8], &As[seg * 16][0]);
      GLDS(&J.Bt[(size_t)(col0 + seg * 16 + dma_r) * K + k0 + dma_c * 8], &Bs[seg * 16][0]);
    }
    __syncthreads();
    short8v af[FR], bf[FR];
#pragma unroll
    for (int i = 0; i < FR; ++i)
      af[i] = *(const short8v*)&As[wm * HALF + i * 16 + l15][(l4 ^ rd_sw) * 8];
#pragma unroll
    for (int j = 0; j < FR; ++j)
      bf[j] = *(const short8v*)&Bs[wn * HALF + j * 16 + l15][(l4 ^ rd_sw) * 8];
#pragma unroll
    for (int i = 0; i < FR; ++i)
#pragma unroll
      for (int j = 0; j < FR; ++j)
        acc[i][j] = __builtin_amdgcn_mfma_f32_16x16x32_bf16(af[i], bf[j], acc[i][j], 0, 0, 0);
  }
#pragma unroll
  for (int i = 0; i < FR; ++i) {
    int rb = row0 + wm * HALF + i * 16 + l4 * 4;
#pragma unroll
    for (int j = 0; j < FR; ++j) {
      int cb = col0 + wn * HALF + j * 16 + l15;
      if (J.trans) {
        __hip_bfloat16 pk[4];
#pragma unroll
        for (int rg = 0; rg < 4; ++rg) pk[rg] = __float2bfloat16(acc[i][j][rg]);
        *(ushort4*)&J.C[(size_t)cb * M + rb] = *(const ushort4*)pk;
      } else {
#pragma unroll
        for (int rg = 0; rg < 4; ++rg)
          J.C[(size_t)(rb + rg) * J.N + cb] = __float2bfloat16(acc[i][j][rg]);
      }
    }
  }
}

// ---------------------------------------------- part1 + part3 (per t row) ---
__global__ __launch_bounds__(256) void part1_kernel(
    const float* __restrict__ s, const float* __restrict__ gv,
    const __hip_bfloat16* __restrict__ q, const __hip_bfloat16* __restrict__ k,
    const __hip_bfloat16* __restrict__ v, const float* __restrict__ r,
    const float* __restrict__ nrw, const float* __restrict__ u0,
    const float* __restrict__ u1, __hip_bfloat16* __restrict__ attn1,
    float* __restrict__ outS) {
  __shared__ float qs[DS];
  __shared__ float dots[NH][N_SLOT];
  __shared__ float wattn[NH][N_SLOT];
  __shared__ float w8[N_SLOT];
  __shared__ float spv[N_SLOT];
  __shared__ float gateL;
  const int t = blockIdx.x;
  const int tid = threadIdx.x;
  for (int i = tid; i < DS; i += 256) qs[i] = __bfloat162float(q[(size_t)t * DS + i]);
  __syncthreads();
  const int wave = tid >> 6, lane = tid & 63;
#pragma unroll
  for (int e = 0; e < 16; ++e) {
    int pair = wave * 16 + e;
    int h = pair >> 3, n = pair & 7;
    const __hip_bfloat16* krow = &k[((size_t)t * N_SLOT + n) * DS + h * DHS];
    float a = qs[h * DHS + lane] * __bfloat162float(krow[lane]) +
              qs[h * DHS + 64 + lane] * __bfloat162float(krow[64 + lane]);
    for (int m = 32; m >= 1; m >>= 1) a += __shfl_xor(a, m);
    if (lane == 0) dots[h][n] = a;
  }
  const float scale_s = 0.08838834764831845f;  // 128^-0.5
#pragma unroll
  for (int e = 0; e < 2; ++e) {
    const int n = wave * 2 + e;
    const float* rr = &r[((size_t)t * N_SLOT + n) * DR];
    const float* ub0 = &u0[(size_t)t * DR];
    const float* ub1 = &u1[(size_t)t * DR];
    float ssum = 0.f, dot = 0.f;
#pragma unroll
    for (int jj = 0; jj < 8; ++jj) {
      int j = lane + 64 * jj;
      float rv = rr[j];
      ssum += rv * rv;
      dot += rv * nrw[j] * (ub0[j] + ub1[j]);
    }
    for (int m = 32; m >= 1; m >>= 1) {
      ssum += __shfl_xor(ssum, m);
      dot += __shfl_xor(dot, m);
    }
    if (lane == 0) {
      float rs = rsqrtf(ssum / (float)DR + 1e-6f);
      spv[n] = scale_s * rs * dot;
    }
  }
  __syncthreads();
  if (tid < 8) {
    int h = tid;
    float vmax = -1e30f;
    for (int n = 0; n < 8; ++n) vmax = fmaxf(vmax, dots[h][n] * scale_s);
    float sum = 0.f;
    for (int n = 0; n < 8; ++n) {
      float e = __expf(dots[h][n] * scale_s - vmax);
      wattn[h][n] = e;
      sum += e;
    }
    float inv = 1.f / sum;
    for (int n = 0; n < 8; ++n) wattn[h][n] *= inv;
  }
  if (tid == 64) {
    float sv[8];
    for (int n = 0; n < 8; ++n) sv[n] = spv[n];
    bool used[8] = {};
    float vals[4];
    int idxs[4];
    for (int kk = 0; kk < 4; ++kk) {
      float best = -1e30f;
      int bi = 0;
      for (int n = 0; n < 8; ++n)
        if (!used[n] && sv[n] > best) { best = sv[n]; bi = n; }
      used[bi] = true;
      vals[kk] = best;
      idxs[kk] = bi;
    }
    float mx = vals[0];
    float wv[4];
    float sum = 0.f;
    for (int kk = 0; kk < 4; ++kk) {
      wv[kk] = __expf(vals[kk] - mx);
      sum += wv[kk];
    }
    float inv = 1.f / sum;
    for (int n = 0; n < 8; ++n) w8[n] = 0.f;
    for (int kk = 0; kk < 4; ++kk) w8[idxs[kk]] = wv[kk] * inv;
    gateL = gv[t];
  }
  __syncthreads();
  const float gate = gateL;
#pragma unroll
  for (int jj = 0; jj < 4; ++jj) {
    int d = tid + 256 * jj;
    int hh = d >> 7;
    float a1 = 0.f, a2 = 0.f;
#pragma unroll
    for (int n = 0; n < 8; ++n) {
      float vv = __bfloat162float(v[((size_t)t * N_SLOT + n) * DS + d]);
      a1 += wattn[hh][n] * vv;
      a2 += w8[n] * vv;
    }
    attn1[(size_t)t * DS + d] = __float2bfloat16(a1);
    outS[(size_t)t * DS + d] = s[(size_t)t * DS + d] + gate * a2;
  }
}

// --------------------------------- part2 MFMA flash attention (S^T form) ----
// Scores computed TRANSPOSED: D[key][qrow] via mfma(kf, qf) so qrow = l15 is
// lane-constant -> softmax reductions are 15 in-reg ops + 2 shuffles (vs 32
// shuffles in row form). PV as O^T = mfma(vf, pf). 64-row Q-tile, 4 waves,
// wave owns one 16-row strip; 36 KB LDS -> 4 blocks/CU.
__global__ __launch_bounds__(256) void flash_mfma_kernel(
    const __hip_bfloat16* __restrict__ qb, const __hip_bfloat16* __restrict__ kb,
    const __hip_bfloat16* __restrict__ vbT, __hip_bfloat16* __restrict__ rat) {
  __shared__ __align__(16) __hip_bfloat16 Qs[64][72];
  __shared__ __align__(16) __hip_bfloat16 Ks[64][72];
  __shared__ __align__(16) __hip_bfloat16 Vt[64][72];  // [dim][key]
  __shared__ __align__(16) __hip_bfloat16 Pb[64][72];  // [qrow][key] wave-local
  const int tid = threadIdx.x;
  const int lane = tid & 63, wave = tid >> 6;
  const int l15 = lane & 15, l4 = lane >> 4;
  const int h = blockIdx.y;
  const int qbase = blockIdx.x * 64;
  const int s = wave * 16;

  for (int g = tid; g < 512; g += 256) {
    int rr = g >> 3, c = (g & 7) * 8;
    *(ulonglong2*)&Qs[rr][c] =
        *(const ulonglong2*)&qb[(size_t)(qbase + rr) * DR + h * DHR + c];
  }
  __syncthreads();
  short8v qf[2];  // B-frag: n = l15 = qrow
#pragma unroll
  for (int kk = 0; kk < 2; ++kk)
    qf[kk] = *(const short8v*)&Qs[s + l15][kk * 32 + l4 * 8];

  const int myt = (qbase + s + l15) >> 3;   // per-lane qrow's t
  const int tmin = (qbase + s) >> 3;        // strip min t (wave-uniform)
  const int tmax = (qbase + s + 15) >> 3;   // strip max t (wave-uniform)

  float m_r = -1e30f, l_r = 0.f;  // per qrow (= l15), replicated across l4
  floatx4 o[4] = {};              // O^T: col = l15 = qrow, row = dim

  const int ntiles = (((qbase + 63) >> 3) >> 6) + 1;
  for (int pt = 0; pt < ntiles; ++pt) {
    const int p0 = pt << 6;
    __syncthreads();
    for (int g = tid; g < 512; g += 256) {
      int rr = g >> 3, c = (g & 7) * 8;
      *(ulonglong2*)&Ks[rr][c] =
          *(const ulonglong2*)&kb[(size_t)(p0 + rr) * DR + h * DHR + c];
      *(ulonglong2*)&Vt[rr][c] =
          *(const ulonglong2*)&vbT[(size_t)(h * DHR + rr) * T_DIM + p0 + c];
    }
    __syncthreads();
    if (p0 > tmax) continue;  // wave-uniform skip
    // S^T = K @ Q^T : lane holds keys p0 + j*16 + l4*4 + rg, qrow = l15
    floatx4 sc[4] = {};
#pragma unroll
    for (int j = 0; j < 4; ++j)
#pragma unroll
      for (int kk = 0; kk < 2; ++kk) {
        short8v kf = *(const short8v*)&Ks[j * 16 + l15][kk * 32 + l4 * 8];
        sc[j] = __builtin_amdgcn_mfma_f32_16x16x32_bf16(kf, qf[kk], sc[j], 0, 0, 0);
      }
    if (p0 + 63 > tmin) {  // causal mask needed in this tile
#pragma unroll
      for (int j = 0; j < 4; ++j)
#pragma unroll
        for (int rg = 0; rg < 4; ++rg)
          if (p0 + j * 16 + l4 * 4 + rg > myt) sc[j][rg] = -1e30f;
    }
    float mx = m_r;
#pragma unroll
    for (int j = 0; j < 4; ++j)
#pragma unroll
      for (int rg = 0; rg < 4; ++rg) mx = fmaxf(mx, sc[j][rg]);
    mx = fmaxf(mx, __shfl_xor(mx, 16));
    mx = fmaxf(mx, __shfl_xor(mx, 32));
    float sum = 0.f;
#pragma unroll
    for (int j = 0; j < 4; ++j)
#pragma unroll
      for (int rg = 0; rg < 4; ++rg) {
        float e = __expf(sc[j][rg] - mx);
        sc[j][rg] = e;
        sum += e;
      }
    sum += __shfl_xor(sum, 16);
    sum += __shfl_xor(sum, 32);
    const float alpha = __expf(m_r - mx);  // lane-scalar (per qrow)
    l_r = alpha * l_r + sum;
    m_r = mx;
    // P -> LDS packed (keys contiguous per lane): Pb[qrow][key]
#pragma unroll
    for (int j = 0; j < 4; ++j) {
      __hip_bfloat16 pk[4];
#pragma unroll
      for (int rg = 0; rg < 4; ++rg) pk[rg] = __float2bfloat16(sc[j][rg]);
      *(ushort4*)&Pb[s + l15][j * 16 + l4 * 4] = *(const ushort4*)pk;
    }
#pragma unroll
    for (int jd = 0; jd < 4; ++jd) o[jd] *= alpha;
    // O^T += V @ P^T : A = Vt rows (dims), B = Pb rows (qrows)
#pragma unroll
    for (int kk = 0; kk < 2; ++kk) {
      short8v pf = *(const short8v*)&Pb[s + l15][kk * 32 + l4 * 8];
#pragma unroll
      for (int jd = 0; jd < 4; ++jd) {
        short8v vf = *(const short8v*)&Vt[jd * 16 + l15][kk * 32 + l4 * 8];
        o[jd] = __builtin_amdgcn_mfma_f32_16x16x32_bf16(vf, pf, o[jd], 0, 0, 0);
      }
    }
  }
  const float inv = 1.f / l_r;
  const size_t rbase = (size_t)(qbase + s + l15) * DR + h * DHR;
#pragma unroll
  for (int jd = 0; jd < 4; ++jd) {
    __hip_bfloat16 pk[4];
#pragma unroll
    for (int rg = 0; rg < 4; ++rg) pk[rg] = __float2bfloat16(o[jd][rg] * inv);
    *(ushort4*)&rat[rbase + jd * 16 + l4 * 4] = *(const ushort4*)pk;
  }
}

// ----------------------------------------------------------------- launch ---
extern "C" void kernel_launch(void* const* d_in, const int* in_sizes, int n_in,
                              void* d_out, int out_size, void* d_ws,
                              size_t ws_size, hipStream_t stream) {
  const float* s   = (const float*)d_in[0];
  const float* r   = (const float*)d_in[1];
  const float* gv  = (const float*)d_in[2];
  const float* nsw = (const float*)d_in[3];
  const float* nrw = (const float*)d_in[4];
  const float* Wsq = (const float*)d_in[5];
  const float* Wsk = (const float*)d_in[6];
  const float* Wsv = (const float*)d_in[7];
  const float* Wso = (const float*)d_in[8];
  const float* Wrq = (const float*)d_in[9];
  const float* Wrk = (const float*)d_in[10];
  const float* Wrv = (const float*)d_in[11];
  const float* Wro = (const float*)d_in[12];

  float* outS = (float*)d_out;   // 1048576 fp32
  float* outR = outS + 1048576;  // 4194304 fp32

  // ---- workspace carve-up ----
  char* wp = (char*)d_ws;
  float* qreg = (float*)wp;           wp += 1048576 * 4;  // s_n32, later q bf16
  __hip_bfloat16* k   = (__hip_bfloat16*)wp; wp += 8388608 * 2;
  __hip_bfloat16* v   = (__hip_bfloat16*)wp; wp += 8388608 * 2;
  __hip_bfloat16* qrb = (__hip_bfloat16*)wp; wp += 4194304 * 2;
  __hip_bfloat16* krb = (__hip_bfloat16*)wp; wp += 524288 * 2;
  __hip_bfloat16* vrbT = (__hip_bfloat16*)wp; wp += 524288 * 2;  // [512][1024]
  __hip_bfloat16* s_nb = (__hip_bfloat16*)wp; wp += 1048576 * 2;
  __hip_bfloat16* r_nb = (__hip_bfloat16*)wp; wp += 4194304 * 2;  // 8 MB region
  __hip_bfloat16* WsqT = (__hip_bfloat16*)wp; wp += 1048576 * 2;
  __hip_bfloat16* WskT = (__hip_bfloat16*)wp; wp += 524288 * 2;
  __hip_bfloat16* WsvT = (__hip_bfloat16*)wp; wp += 524288 * 2;
  __hip_bfloat16* WsoT = (__hip_bfloat16*)wp; wp += 1048576 * 2;
  __hip_bfloat16* WrqT = (__hip_bfloat16*)wp; wp += 262144 * 2;
  __hip_bfloat16* WrkT = (__hip_bfloat16*)wp; wp += 524288 * 2;
  __hip_bfloat16* WrvT = (__hip_bfloat16*)wp; wp += 524288 * 2;
  __hip_bfloat16* WroT = (__hip_bfloat16*)wp; wp += 262144 * 2;

  // Overlays in r_nb's 8 MB region (r_nb dead after batchA):
  float* s_n32 = qreg;                         // dead before batchB writes q
  __hip_bfloat16* q = (__hip_bfloat16*)qreg;
  float* Wc01 = (float*)r_nb;                  // Wc partials: 2 x 2 MB
  float* u0   = (float*)((char*)r_nb + 4194304);  // u partials: 2 x 2 MB
  float* u1   = (float*)((char*)r_nb + 6291456);
  __hip_bfloat16* attn1b = s_nb;               // s_nb dead after batchB
  __hip_bfloat16* ratb   = r_nb;               // Wc/u dead after part1

  // 1) prep: weight transposes (Wrq pre-scaled 2^-3) + rmsnorms
  TJobs jobs = {{
      {Wsq, WsqT, 1024, 1024, 1.f, 0},
      {Wsk, WskT, 512, 1024, 1.f, 1024},
      {Wsv, WsvT, 512, 1024, 1.f, 1536},
      {Wso, WsoT, 1024, 1024, 1.f, 2048},
      {Wrq, WrqT, 512, 512, 0.125f, 3072},
      {Wrk, WrkT, 1024, 512, 1.f, 3328},
      {Wrv, WrvT, 1024, 512, 1.f, 3840},
      {Wro, WroT, 512, 512, 1.f, 4352},
  }};
  prep_kernel<<<13824, 256, 0, stream>>>(jobs, s, r, nsw, nrw, s_nb, s_n32, r_nb);

  // 2) batchA: k/v/qr GEMMs from r_nb (must precede Wc overlay write)
  GJobs ga = {{
      {WskT, k, 1024, 0, 0},
      {WsvT, v, 1024, 512, 0},
      {WrqT, qrb, 512, 1024, 0},
  }};
  mfma_gemm_batch_kernel<128><<<1280, 256, 0, stream>>>(r_nb, ga, 8192, 512);

  // 3) Wc = Wsq @ Wsk^T (fp32, split-K partials into Wc01)
  gemm_f32_kernel<64, 4, true, false><<<dim3(8, 16, 2), 256, 0, stream>>>(Wsq, Wsk, Wc01, 1024, 512, 1024);

  // 4) u = s_n32 @ (Wc0+Wc1) (fp32, split-K partials u0/u1)
  gemm_f32_kernel<64, 4, false, true><<<dim3(8, 16, 2), 256, 0, stream>>>(s_n32, Wc01, u0, 1024, 512, 1024);

  // 5) batchB: q/kr/vrT GEMMs from s_nb (q overwrites s_n32 — dead after u)
  GJobs gb = {{
      {WsqT, q, 1024, 0, 0},
      {WrkT, krb, 512, 256, 0},
      {WrvT, vrbT, 512, 384, 1},
  }};
  mfma_gemm_batch_kernel<64><<<512, 256, 0, stream>>>(s_nb, gb, 1024, 1024);

  // 6) part 1 + part 3
  part1_kernel<<<1024, 256, 0, stream>>>(s, gv, q, k, v, r, nrw, u0, u1, attn1b, outS);

  // 7) outS += attn1 @ Wso
  mfma_gemm_kernel<64, true, float><<<dim3(16, 16), 256, 0, stream>>>(attn1b, WsoT, outS, nullptr, 1024, 1024, 1024);

  // 8) flash (S^T softmax)
  flash_mfma_kernel<<<dim3(128, 8), 256, 0, stream>>>(qrb, krb, vrbT, ratb);

  // 9) outR = r + rat @ Wro (fused epilogue)
  mfma_gemm_kernel<128, false, float, true><<<dim3(4, 64), 256, 0, stream>>>(ratb, WroT, outR, r, 8192, 512, 512);
}

// Round 9
// 318.926 us; speedup vs baseline: 3.9918x; 1.0088x over previous
//
#include <hip/hip_runtime.h>
#include <hip/hip_bf16.h>
#include <math.h>
#include <type_traits>

// ---------------------------------------------------------------------------
// BridgeLayer: XCD-swizzled bf16-MFMA GEMMs (global_load_lds) + S^T MFMA flash
// (Qs/Pb LDS alias); fp32 split-K top-k score path; vectorized part1.
// B=1,T=1024,N=8,H=8,D_S=1024,D_R=512,TOPK=4
// ---------------------------------------------------------------------------

#define T_DIM 1024
#define N_SLOT 8
#define DS 1024
#define DR 512
#define NH 8
#define DHS 128
#define DHR 64

typedef __attribute__((ext_vector_type(8))) short short8v;
typedef __attribute__((ext_vector_type(4))) float floatx4;

#define GLDS(gptr, lptr)                                                     \
  __builtin_amdgcn_global_load_lds(                                          \
      (__attribute__((address_space(1))) void*)(gptr),                       \
      (__attribute__((address_space(3))) void*)(lptr), 16, 0, 0)

// XCD chunk swizzle: blocks with id%8==x (resident on XCD x) get a contiguous
// slab of work ids -> per-XCD L2 sees a contiguous A-row slab (no cross-XCD
// re-fetch). Bijection on [0,G).
__device__ inline int xcd_swz(int b, int G) {
  int per = G >> 3, rem = G & 7;
  int x = b & 7, i = b >> 3;
  return x * per + (x < rem ? x : rem) + i;
}

__device__ inline float bf_lo(unsigned int u) {
  unsigned short x = (unsigned short)(u & 0xffff);
  __hip_bfloat16 b;
  __builtin_memcpy(&b, &x, 2);
  return __bfloat162float(b);
}
__device__ inline float bf_hi(unsigned int u) {
  unsigned short x = (unsigned short)(u >> 16);
  __hip_bfloat16 b;
  __builtin_memcpy(&b, &x, 2);
  return __bfloat162float(b);
}

// ---------------------------------------- prep: transposes + rmsnorms -------
struct TJob { const float* W; __hip_bfloat16* Wt; int K; int N; float scale; int b0; };
struct TJobs { TJob j[8]; };

__global__ __launch_bounds__(256) void prep_kernel(
    TJobs jobs, const float* __restrict__ s, const float* __restrict__ r,
    const float* __restrict__ nsw, const float* __restrict__ nrw,
    __hip_bfloat16* __restrict__ s_nb, float* __restrict__ s_n32,
    __hip_bfloat16* __restrict__ r_nb) {
  __shared__ float sh[32][33];
  const int tid = threadIdx.x;
  if (blockIdx.x < 4608) {
    int ji = 0;
#pragma unroll
    for (int t = 1; t < 8; ++t)
      if ((int)blockIdx.x >= jobs.j[t].b0) ji = t;
    const TJob J = jobs.j[ji];
    const int lb = blockIdx.x - J.b0;
    const int nbx = J.N >> 5;
    const int n0 = (lb % nbx) * 32, k0 = (lb / nbx) * 32;
    const int tx = tid & 31, ty = tid >> 5;
#pragma unroll
    for (int i = 0; i < 4; ++i) {
      int kk = ty + i * 8;
      sh[kk][tx] = J.W[(size_t)(k0 + kk) * J.N + n0 + tx];
    }
    __syncthreads();
#pragma unroll
    for (int i = 0; i < 4; ++i) {
      int nn = ty + i * 8;
      J.Wt[(size_t)(n0 + nn) * J.K + k0 + tx] = __float2bfloat16(sh[tx][nn] * J.scale);
    }
  } else {
    const int blk = blockIdx.x - 4608;
    const bool is_s = blk < 1024;
    const int row = is_s ? blk : blk - 1024;
    const int width = is_s ? DS : DR;
    const float* x = is_s ? s : r;
    const float* w = is_s ? nsw : nrw;
    const size_t base = (size_t)row * width;
    float ss = 0.f;
    for (int i = tid; i < width; i += 256) {
      float v = x[base + i];
      ss += v * v;
    }
    for (int m = 32; m >= 1; m >>= 1) ss += __shfl_xor(ss, m);
    const int wave = tid >> 6, lane = tid & 63;
    if (lane == 0) sh[0][wave] = ss;
    __syncthreads();
    float total = sh[0][0] + sh[0][1] + sh[0][2] + sh[0][3];
    float scale = rsqrtf(total / (float)width + 1e-6f);
    for (int i = tid; i < width; i += 256) {
      float val = x[base + i] * scale * w[i];
      if (is_s) {
        s_nb[base + i] = __float2bfloat16(val);
        s_n32[base + i] = val;
      } else {
        r_nb[base + i] = __float2bfloat16(val);
      }
    }
  }
}

// ------------------------------------------------ fp32 gemm (split-K, z=2) --
template <int BS, int TT, bool BT, bool BSUM>
__global__ __launch_bounds__(256) void gemm_f32_kernel(
    const float* __restrict__ A, const float* __restrict__ B,
    float* __restrict__ C, int M, int N, int K) {
  __shared__ __align__(16) float Ast[16][BS + 4];
  __shared__ __align__(16) float Bs[16][BS + 4];
  const int tid = threadIdx.x;
  const int tx = tid & 15, ty = tid >> 4;
  const int row0 = blockIdx.y * BS, col0 = blockIdx.x * BS;
  const int kz = blockIdx.z;
  const int kbeg = kz * (K >> 1), kend = kbeg + (K >> 1);
  float* Cz = C + (size_t)kz * M * N;
  const size_t bsz = (size_t)K * N;
  float acc[TT][TT] = {};
  constexpr int NF4 = BS * 16 / 4;
  for (int k0 = kbeg; k0 < kend; k0 += 16) {
    __syncthreads();
    for (int l = tid; l < NF4; l += 256) {
      int lr = l >> 2, lk = (l & 3) << 2;
      float4 a4 = *(const float4*)&A[(size_t)(row0 + lr) * K + k0 + lk];
      Ast[lk + 0][lr] = a4.x;
      Ast[lk + 1][lr] = a4.y;
      Ast[lk + 2][lr] = a4.z;
      Ast[lk + 3][lr] = a4.w;
      if (BT) {
        float4 b4 = *(const float4*)&B[(size_t)(col0 + lr) * K + k0 + lk];
        Bs[lk + 0][lr] = b4.x;
        Bs[lk + 1][lr] = b4.y;
        Bs[lk + 2][lr] = b4.z;
        Bs[lk + 3][lr] = b4.w;
      } else {
        int bkk = l / (BS / 4), bc = (l % (BS / 4)) << 2;
        size_t bidx = (size_t)(k0 + bkk) * N + col0 + bc;
        float4 b4 = *(const float4*)&B[bidx];
        if (BSUM) {
          float4 b2 = *(const float4*)&B[bsz + bidx];
          b4.x += b2.x; b4.y += b2.y; b4.z += b2.z; b4.w += b2.w;
        }
        *(float4*)&Bs[bkk][bc] = b4;
      }
    }
    __syncthreads();
#pragma unroll
    for (int kk = 0; kk < 16; ++kk) {
      float av[TT], bv[TT];
#pragma unroll
      for (int u = 0; u < TT; u += 4) {
        *(float4*)&av[u] = *(const float4*)&Ast[kk][ty * TT + u];
        *(float4*)&bv[u] = *(const float4*)&Bs[kk][tx * TT + u];
      }
#pragma unroll
      for (int i = 0; i < TT; ++i)
#pragma unroll
        for (int j = 0; j < TT; ++j) acc[i][j] += av[i] * bv[j];
    }
  }
#pragma unroll
  for (int i = 0; i < TT; ++i) {
    size_t crow = (size_t)(row0 + ty * TT + i) * N + col0;
#pragma unroll
    for (int j = 0; j < TT; j += 4) {
      *(float4*)&Cz[crow + tx * TT + j] =
          make_float4(acc[i][j], acc[i][j + 1], acc[i][j + 2], acc[i][j + 3]);
    }
  }
}

// -------------------------------------------------------------- MFMA gemm ---
// 1D grid + XCD swizzle. C (+)= A[M,K] @ Bt[N,K]^T.  RADD: C = R + acc.
template <int MT, bool ACCUM, typename OutT, bool RADD = false>
__global__ __launch_bounds__(256) void mfma_gemm_kernel(
    const __hip_bfloat16* __restrict__ A, const __hip_bfloat16* __restrict__ Bt,
    OutT* __restrict__ C, const float* __restrict__ R, int M, int N, int K,
    int nbx) {
  constexpr int FR = MT / 32;
  constexpr int HALF = MT / 2;
  constexpr int SEG_PER_WAVE = MT / 16 / 4;
  __shared__ __hip_bfloat16 As[MT][32];
  __shared__ __hip_bfloat16 Bs[MT][32];
  const int sb = xcd_swz(blockIdx.x, gridDim.x);
  const int row0 = (sb / nbx) * MT, col0 = (sb % nbx) * MT;
  const int tid = threadIdx.x;
  const int lane = tid & 63, wave = tid >> 6;
  const int wm = wave >> 1, wn = wave & 1;
  const int l15 = lane & 15, l4 = lane >> 4;
  const int dma_r = lane >> 2;
  const int dma_c = (lane & 3) ^ ((lane >> 3) & 3);
  const int rd_sw = (l15 >> 1) & 3;
  floatx4 acc[FR][FR] = {};
  for (int k0 = 0; k0 < K; k0 += 32) {
    __syncthreads();
#pragma unroll
    for (int i = 0; i < SEG_PER_WAVE; ++i) {
      int seg = wave * SEG_PER_WAVE + i;
      GLDS(&A[(size_t)(row0 + seg * 16 + dma_r) * K + k0 + dma_c * 8], &As[seg * 16][0]);
      GLDS(&Bt[(size_t)(col0 + seg * 16 + dma_r) * K + k0 + dma_c * 8], &Bs[seg * 16][0]);
    }
    __syncthreads();
    short8v af[FR], bf[FR];
#pragma unroll
    for (int i = 0; i < FR; ++i)
      af[i] = *(const short8v*)&As[wm * HALF + i * 16 + l15][(l4 ^ rd_sw) * 8];
#pragma unroll
    for (int j = 0; j < FR; ++j)
      bf[j] = *(const short8v*)&Bs[wn * HALF + j * 16 + l15][(l4 ^ rd_sw) * 8];
#pragma unroll
    for (int i = 0; i < FR; ++i)
#pragma unroll
      for (int j = 0; j < FR; ++j)
        acc[i][j] = __builtin_amdgcn_mfma_f32_16x16x32_bf16(af[i], bf[j], acc[i][j], 0, 0, 0);
  }
#pragma unroll
  for (int i = 0; i < FR; ++i) {
    int rb = row0 + wm * HALF + i * 16 + l4 * 4;
#pragma unroll
    for (int j = 0; j < FR; ++j) {
      int cb = col0 + wn * HALF + j * 16 + l15;
#pragma unroll
      for (int rg = 0; rg < 4; ++rg) {
        size_t idx = (size_t)(rb + rg) * N + cb;
        if constexpr (std::is_same<OutT, __hip_bfloat16>::value) {
          C[idx] = __float2bfloat16(acc[i][j][rg]);
        } else if constexpr (RADD) {
          C[idx] = R[idx] + acc[i][j][rg];
        } else if constexpr (ACCUM) {
          C[idx] += acc[i][j][rg];
        } else {
          C[idx] = acc[i][j][rg];
        }
      }
    }
  }
}

// Batched version: shared A, per-job Bt/C/N, bf16 out, runtime trans flag.
struct GJob { const __hip_bfloat16* Bt; __hip_bfloat16* C; int N; int b0; int trans; };
struct GJobs { GJob j[3]; };

template <int MT>
__global__ __launch_bounds__(256) void mfma_gemm_batch_kernel(
    const __hip_bfloat16* __restrict__ A, GJobs jobs, int M, int K) {
  constexpr int FR = MT / 32;
  constexpr int HALF = MT / 2;
  constexpr int SEG_PER_WAVE = MT / 16 / 4;
  __shared__ __hip_bfloat16 As[MT][32];
  __shared__ __hip_bfloat16 Bs[MT][32];
  const int sb = xcd_swz(blockIdx.x, gridDim.x);
  int ji = 0;
#pragma unroll
  for (int t = 1; t < 3; ++t)
    if (sb >= jobs.j[t].b0) ji = t;
  const GJob J = jobs.j[ji];
  const int lb = sb - J.b0;
  const int nbx = J.N / MT;
  const int row0 = (lb / nbx) * MT, col0 = (lb % nbx) * MT;
  const int tid = threadIdx.x;
  const int lane = tid & 63, wave = tid >> 6;
  const int wm = wave >> 1, wn = wave & 1;
  const int l15 = lane & 15, l4 = lane >> 4;
  const int dma_r = lane >> 2;
  const int dma_c = (lane & 3) ^ ((lane >> 3) & 3);
  const int rd_sw = (l15 >> 1) & 3;
  floatx4 acc[FR][FR] = {};
  for (int k0 = 0; k0 < K; k0 += 32) {
    __syncthreads();
#pragma unroll
    for (int i = 0; i < SEG_PER_WAVE; ++i) {
      int seg = wave * SEG_PER_WAVE + i;
      GLDS(&A[(size_t)(row0 + seg * 16 + dma_r) * K + k0 + dma_c * 8], &As[seg * 16][0]);
      GLDS(&J.Bt[(size_t)(col0 + seg * 16 + dma_r) * K + k0 + dma_c * 8], &Bs[seg * 16][0]);
    }
    __syncthreads();
    short8v af[FR], bf[FR];
#pragma unroll
    for (int i = 0; i < FR; ++i)
      af[i] = *(const short8v*)&As[wm * HALF + i * 16 + l15][(l4 ^ rd_sw) * 8];
#pragma unroll
    for (int j = 0; j < FR; ++j)
      bf[j] = *(const short8v*)&Bs[wn * HALF + j * 16 + l15][(l4 ^ rd_sw) * 8];
#pragma unroll
    for (int i = 0; i < FR; ++i)
#pragma unroll
      for (int j = 0; j < FR; ++j)
        acc[i][j] = __builtin_amdgcn_mfma_f32_16x16x32_bf16(af[i], bf[j], acc[i][j], 0, 0, 0);
  }
#pragma unroll
  for (int i = 0; i < FR; ++i) {
    int rb = row0 + wm * HALF + i * 16 + l4 * 4;
#pragma unroll
    for (int j = 0; j < FR; ++j) {
      int cb = col0 + wn * HALF + j * 16 + l15;
      if (J.trans) {
        __hip_bfloat16 pk[4];
#pragma unroll
        for (int rg = 0; rg < 4; ++rg) pk[rg] = __float2bfloat16(acc[i][j][rg]);
        *(ushort4*)&J.C[(size_t)cb * M + rb] = *(const ushort4*)pk;
      } else {
#pragma unroll
        for (int rg = 0; rg < 4; ++rg)
          J.C[(size_t)(rb + rg) * J.N + cb] = __float2bfloat16(acc[i][j][rg]);
      }
    }
  }
}

// ---------------------------------------------- part1 + part3 (per t row) ---
// Vectorized bf16x2 / float2 memory path.
__global__ __launch_bounds__(256) void part1_kernel(
    const float* __restrict__ s, const float* __restrict__ gv,
    const __hip_bfloat16* __restrict__ q, const __hip_bfloat16* __restrict__ k,
    const __hip_bfloat16* __restrict__ v, const float* __restrict__ r,
    const float* __restrict__ nrw, const float* __restrict__ u0,
    const float* __restrict__ u1, __hip_bfloat16* __restrict__ attn1,
    float* __restrict__ outS) {
  __shared__ float qs[DS];
  __shared__ float dots[NH][N_SLOT];
  __shared__ float wattn[NH][N_SLOT];
  __shared__ float w8[N_SLOT];
  __shared__ float spv[N_SLOT];
  __shared__ float gateL;
  const int t = blockIdx.x;
  const int tid = threadIdx.x;
  {
    const unsigned int* q2 = (const unsigned int*)&q[(size_t)t * DS];
    for (int i = tid; i < DS / 2; i += 256) {
      unsigned int pk = q2[i];
      qs[2 * i] = bf_lo(pk);
      qs[2 * i + 1] = bf_hi(pk);
    }
  }
  __syncthreads();
  const int wave = tid >> 6, lane = tid & 63;
#pragma unroll
  for (int e = 0; e < 16; ++e) {
    int pair = wave * 16 + e;
    int h = pair >> 3, n = pair & 7;
    const unsigned int* kr2 =
        (const unsigned int*)&k[((size_t)t * N_SLOT + n) * DS + h * DHS];
    unsigned int pk = kr2[lane];  // elements 2*lane, 2*lane+1 of head slice
    float a = qs[h * DHS + 2 * lane] * bf_lo(pk) +
              qs[h * DHS + 2 * lane + 1] * bf_hi(pk);
    for (int m = 32; m >= 1; m >>= 1) a += __shfl_xor(a, m);
    if (lane == 0) dots[h][n] = a;
  }
  const float scale_s = 0.08838834764831845f;  // 128^-0.5
#pragma unroll
  for (int e = 0; e < 2; ++e) {
    const int n = wave * 2 + e;
    const float* rr = &r[((size_t)t * N_SLOT + n) * DR];
    const float* ub0 = &u0[(size_t)t * DR];
    const float* ub1 = &u1[(size_t)t * DR];
    float ssum = 0.f, dot = 0.f;
#pragma unroll
    for (int jj = 0; jj < 8; ++jj) {
      int j = lane + 64 * jj;
      float rv = rr[j];
      ssum += rv * rv;
      dot += rv * nrw[j] * (ub0[j] + ub1[j]);
    }
    for (int m = 32; m >= 1; m >>= 1) {
      ssum += __shfl_xor(ssum, m);
      dot += __shfl_xor(dot, m);
    }
    if (lane == 0) {
      float rs = rsqrtf(ssum / (float)DR + 1e-6f);
      spv[n] = scale_s * rs * dot;
    }
  }
  __syncthreads();
  if (tid < 8) {
    int h = tid;
    float vmax = -1e30f;
    for (int n = 0; n < 8; ++n) vmax = fmaxf(vmax, dots[h][n] * scale_s);
    float sum = 0.f;
    for (int n = 0; n < 8; ++n) {
      float e = __expf(dots[h][n] * scale_s - vmax);
      wattn[h][n] = e;
      sum += e;
    }
    float inv = 1.f / sum;
    for (int n = 0; n < 8; ++n) wattn[h][n] *= inv;
  }
  if (tid == 64) {
    float sv[8];
    for (int n = 0; n < 8; ++n) sv[n] = spv[n];
    bool used[8] = {};
    float vals[4];
    int idxs[4];
    for (int kk = 0; kk < 4; ++kk) {
      float best = -1e30f;
      int bi = 0;
      for (int n = 0; n < 8; ++n)
        if (!used[n] && sv[n] > best) { best = sv[n]; bi = n; }
      used[bi] = true;
      vals[kk] = best;
      idxs[kk] = bi;
    }
    float mx = vals[0];
    float wv[4];
    float sum = 0.f;
    for (int kk = 0; kk < 4; ++kk) {
      wv[kk] = __expf(vals[kk] - mx);
      sum += wv[kk];
    }
    float inv = 1.f / sum;
    for (int n = 0; n < 8; ++n) w8[n] = 0.f;
    for (int kk = 0; kk < 4; ++kk) w8[idxs[kk]] = wv[kk] * inv;
    gateL = gv[t];
  }
  __syncthreads();
  const float gate = gateL;
#pragma unroll
  for (int jj = 0; jj < 2; ++jj) {
    int dp = tid + 256 * jj;  // pair index in [0, 512)
    int hh = dp >> 6;         // (2*dp)>>7
    float a1x = 0.f, a1y = 0.f, a2x = 0.f, a2y = 0.f;
#pragma unroll
    for (int n = 0; n < 8; ++n) {
      unsigned int pv =
          ((const unsigned int*)&v[((size_t)t * N_SLOT + n) * DS])[dp];
      float vx = bf_lo(pv), vy = bf_hi(pv);
      float wa = wattn[hh][n], wb = w8[n];
      a1x += wa * vx; a1y += wa * vy;
      a2x += wb * vx; a2y += wb * vy;
    }
    __hip_bfloat16 pk2[2] = {__float2bfloat16(a1x), __float2bfloat16(a1y)};
    ((unsigned int*)&attn1[(size_t)t * DS])[dp] = *(const unsigned int*)pk2;
    float2 sv = ((const float2*)&s[(size_t)t * DS])[dp];
    ((float2*)&outS[(size_t)t * DS])[dp] =
        make_float2(sv.x + gate * a2x, sv.y + gate * a2y);
  }
}

// --------------------------------- part2 MFMA flash attention (S^T form) ----
// Qs aliased with Pb (Qs dead after qf extraction; loop-entry barrier orders
// all Qs reads before any Pb write). 27 KB LDS -> 5 blocks/CU.
__global__ __launch_bounds__(256) void flash_mfma_kernel(
    const __hip_bfloat16* __restrict__ qb, const __hip_bfloat16* __restrict__ kb,
    const __hip_bfloat16* __restrict__ vbT, __hip_bfloat16* __restrict__ rat) {
  __shared__ __align__(16) __hip_bfloat16 QP[64][72];  // Qs, then Pb[qrow][key]
  __shared__ __align__(16) __hip_bfloat16 Ks[64][72];
  __shared__ __align__(16) __hip_bfloat16 Vt[64][72];  // [dim][key]
  const int tid = threadIdx.x;
  const int lane = tid & 63, wave = tid >> 6;
  const int l15 = lane & 15, l4 = lane >> 4;
  const int h = blockIdx.y;
  const int qbase = blockIdx.x * 64;
  const int s = wave * 16;

  for (int g = tid; g < 512; g += 256) {
    int rr = g >> 3, c = (g & 7) * 8;
    *(ulonglong2*)&QP[rr][c] =
        *(const ulonglong2*)&qb[(size_t)(qbase + rr) * DR + h * DHR + c];
  }
  __syncthreads();
  short8v qf[2];  // B-frag: n = l15 = qrow
#pragma unroll
  for (int kk = 0; kk < 2; ++kk)
    qf[kk] = *(const short8v*)&QP[s + l15][kk * 32 + l4 * 8];

  const int myt = (qbase + s + l15) >> 3;
  const int tmin = (qbase + s) >> 3;
  const int tmax = (qbase + s + 15) >> 3;

  float m_r = -1e30f, l_r = 0.f;
  floatx4 o[4] = {};  // O^T: col = l15 = qrow, row = dim

  const int ntiles = (((qbase + 63) >> 3) >> 6) + 1;
  for (int pt = 0; pt < ntiles; ++pt) {
    const int p0 = pt << 6;
    __syncthreads();
    for (int g = tid; g < 512; g += 256) {
      int rr = g >> 3, c = (g & 7) * 8;
      *(ulonglong2*)&Ks[rr][c] =
          *(const ulonglong2*)&kb[(size_t)(p0 + rr) * DR + h * DHR + c];
      *(ulonglong2*)&Vt[rr][c] =
          *(const ulonglong2*)&vbT[(size_t)(h * DHR + rr) * T_DIM + p0 + c];
    }
    __syncthreads();
    if (p0 > tmax) continue;  // wave-uniform skip
    floatx4 sc[4] = {};
#pragma unroll
    for (int j = 0; j < 4; ++j)
#pragma unroll
      for (int kk = 0; kk < 2; ++kk) {
        short8v kf = *(const short8v*)&Ks[j * 16 + l15][kk * 32 + l4 * 8];
        sc[j] = __builtin_amdgcn_mfma_f32_16x16x32_bf16(kf, qf[kk], sc[j], 0, 0, 0);
      }
    if (p0 + 63 > tmin) {
#pragma unroll
      for (int j = 0; j < 4; ++j)
#pragma unroll
        for (int rg = 0; rg < 4; ++rg)
          if (p0 + j * 16 + l4 * 4 + rg > myt) sc[j][rg] = -1e30f;
    }
    float mx = m_r;
#pragma unroll
    for (int j = 0; j < 4; ++j)
#pragma unroll
      for (int rg = 0; rg < 4; ++rg) mx = fmaxf(mx, sc[j][rg]);
    mx = fmaxf(mx, __shfl_xor(mx, 16));
    mx = fmaxf(mx, __shfl_xor(mx, 32));
    float sum = 0.f;
#pragma unroll
    for (int j = 0; j < 4; ++j)
#pragma unroll
      for (int rg = 0; rg < 4; ++rg) {
        float e = __expf(sc[j][rg] - mx);
        sc[j][rg] = e;
        sum += e;
      }
    sum += __shfl_xor(sum, 16);
    sum += __shfl_xor(sum, 32);
    const float alpha = __expf(m_r - mx);
    l_r = alpha * l_r + sum;
    m_r = mx;
#pragma unroll
    for (int j = 0; j < 4; ++j) {
      __hip_bfloat16 pk[4];
#pragma unroll
      for (int rg = 0; rg < 4; ++rg) pk[rg] = __float2bfloat16(sc[j][rg]);
      *(ushort4*)&QP[s + l15][j * 16 + l4 * 4] = *(const ushort4*)pk;
    }
#pragma unroll
    for (int jd = 0; jd < 4; ++jd) o[jd] *= alpha;
#pragma unroll
    for (int kk = 0; kk < 2; ++kk) {
      short8v pf = *(const short8v*)&QP[s + l15][kk * 32 + l4 * 8];
#pragma unroll
      for (int jd = 0; jd < 4; ++jd) {
        short8v vf = *(const short8v*)&Vt[jd * 16 + l15][kk * 32 + l4 * 8];
        o[jd] = __builtin_amdgcn_mfma_f32_16x16x32_bf16(vf, pf, o[jd], 0, 0, 0);
      }
    }
  }
  const float inv = 1.f / l_r;
  const size_t rbase = (size_t)(qbase + s + l15) * DR + h * DHR;
#pragma unroll
  for (int jd = 0; jd < 4; ++jd) {
    __hip_bfloat16 pk[4];
#pragma unroll
    for (int rg = 0; rg < 4; ++rg) pk[rg] = __float2bfloat16(o[jd][rg] * inv);
    *(ushort4*)&rat[rbase + jd * 16 + l4 * 4] = *(const ushort4*)pk;
  }
}

// ----------------------------------------------------------------- launch ---
extern "C" void kernel_launch(void* const* d_in, const int* in_sizes, int n_in,
                              void* d_out, int out_size, void* d_ws,
                              size_t ws_size, hipStream_t stream) {
  const float* s   = (const float*)d_in[0];
  const float* r   = (const float*)d_in[1];
  const float* gv  = (const float*)d_in[2];
  const float* nsw = (const float*)d_in[3];
  const float* nrw = (const float*)d_in[4];
  const float* Wsq = (const float*)d_in[5];
  const float* Wsk = (const float*)d_in[6];
  const float* Wsv = (const float*)d_in[7];
  const float* Wso = (const float*)d_in[8];
  const float* Wrq = (const float*)d_in[9];
  const float* Wrk = (const float*)d_in[10];
  const float* Wrv = (const float*)d_in[11];
  const float* Wro = (const float*)d_in[12];

  float* outS = (float*)d_out;   // 1048576 fp32
  float* outR = outS + 1048576;  // 4194304 fp32

  // ---- workspace carve-up ----
  char* wp = (char*)d_ws;
  float* qreg = (float*)wp;           wp += 1048576 * 4;  // s_n32, later q bf16
  __hip_bfloat16* k   = (__hip_bfloat16*)wp; wp += 8388608 * 2;
  __hip_bfloat16* v   = (__hip_bfloat16*)wp; wp += 8388608 * 2;
  __hip_bfloat16* qrb = (__hip_bfloat16*)wp; wp += 4194304 * 2;
  __hip_bfloat16* krb = (__hip_bfloat16*)wp; wp += 524288 * 2;
  __hip_bfloat16* vrbT = (__hip_bfloat16*)wp; wp += 524288 * 2;  // [512][1024]
  __hip_bfloat16* s_nb = (__hip_bfloat16*)wp; wp += 1048576 * 2;
  __hip_bfloat16* r_nb = (__hip_bfloat16*)wp; wp += 4194304 * 2;  // 8 MB region
  __hip_bfloat16* WsqT = (__hip_bfloat16*)wp; wp += 1048576 * 2;
  __hip_bfloat16* WskT = (__hip_bfloat16*)wp; wp += 524288 * 2;
  __hip_bfloat16* WsvT = (__hip_bfloat16*)wp; wp += 524288 * 2;
  __hip_bfloat16* WsoT = (__hip_bfloat16*)wp; wp += 1048576 * 2;
  __hip_bfloat16* WrqT = (__hip_bfloat16*)wp; wp += 262144 * 2;
  __hip_bfloat16* WrkT = (__hip_bfloat16*)wp; wp += 524288 * 2;
  __hip_bfloat16* WrvT = (__hip_bfloat16*)wp; wp += 524288 * 2;
  __hip_bfloat16* WroT = (__hip_bfloat16*)wp; wp += 262144 * 2;

  // Overlays in r_nb's 8 MB region (r_nb dead after batchA):
  float* s_n32 = qreg;
  __hip_bfloat16* q = (__hip_bfloat16*)qreg;
  float* Wc01 = (float*)r_nb;
  float* u0   = (float*)((char*)r_nb + 4194304);
  float* u1   = (float*)((char*)r_nb + 6291456);
  __hip_bfloat16* attn1b = s_nb;
  __hip_bfloat16* ratb   = r_nb;

  // 1) prep: weight transposes (Wrq pre-scaled 2^-3) + rmsnorms
  TJobs jobs = {{
      {Wsq, WsqT, 1024, 1024, 1.f, 0},
      {Wsk, WskT, 512, 1024, 1.f, 1024},
      {Wsv, WsvT, 512, 1024, 1.f, 1536},
      {Wso, WsoT, 1024, 1024, 1.f, 2048},
      {Wrq, WrqT, 512, 512, 0.125f, 3072},
      {Wrk, WrkT, 1024, 512, 1.f, 3328},
      {Wrv, WrvT, 1024, 512, 1.f, 3840},
      {Wro, WroT, 512, 512, 1.f, 4352},
  }};
  prep_kernel<<<13824, 256, 0, stream>>>(jobs, s, r, nsw, nrw, s_nb, s_n32, r_nb);

  // 2) batchA: k/v/qr GEMMs from r_nb
  GJobs ga = {{
      {WskT, k, 1024, 0, 0},
      {WsvT, v, 1024, 512, 0},
      {WrqT, qrb, 512, 1024, 0},
  }};
  mfma_gemm_batch_kernel<128><<<1280, 256, 0, stream>>>(r_nb, ga, 8192, 512);

  // 3) Wc = Wsq @ Wsk^T (fp32, split-K partials into Wc01)
  gemm_f32_kernel<64, 4, true, false><<<dim3(8, 16, 2), 256, 0, stream>>>(Wsq, Wsk, Wc01, 1024, 512, 1024);

  // 4) u = s_n32 @ (Wc0+Wc1) (fp32, split-K partials u0/u1)
  gemm_f32_kernel<64, 4, false, true><<<dim3(8, 16, 2), 256, 0, stream>>>(s_n32, Wc01, u0, 1024, 512, 1024);

  // 5) batchB: q/kr/vrT GEMMs from s_nb (q overwrites s_n32 — dead after u)
  GJobs gb = {{
      {WsqT, q, 1024, 0, 0},
      {WrkT, krb, 512, 256, 0},
      {WrvT, vrbT, 512, 384, 1},
  }};
  mfma_gemm_batch_kernel<64><<<512, 256, 0, stream>>>(s_nb, gb, 1024, 1024);

  // 6) part 1 + part 3
  part1_kernel<<<1024, 256, 0, stream>>>(s, gv, q, k, v, r, nrw, u0, u1, attn1b, outS);

  // 7) outS += attn1 @ Wso
  mfma_gemm_kernel<64, true, float><<<256, 256, 0, stream>>>(attn1b, WsoT, outS, nullptr, 1024, 1024, 1024, 16);

  // 8) flash (S^T softmax, Qs/Pb alias)
  flash_mfma_kernel<<<dim3(128, 8), 256, 0, stream>>>(qrb, krb, vrbT, ratb);

  // 9) outR = r + rat @ Wro (fused epilogue)
  mfma_gemm_kernel<128, false, float, true><<<256, 256, 0, stream>>>(ratb, WroT, outR, r, 8192, 512, 512, 4);
}